// Round 3
// baseline (427.545 us; speedup 1.0000x reference)
//
#include <hip/hip_runtime.h>
#include <hip/hip_fp16.h>

// ---------------------------------------------------------------------------
// 2-layer GCN on MI355X.
//   GCNConv(x) = A_hat (x W) + b = (A_hat x) W + b  (agg and linear commute),
//   and emb[labels]@W1 = (emb@W1)[labels] -> layer 1 gathers from a 512KB
//   L2-resident table; layer 2 aggregates first, then in-place GEMM on d_out.
// CSR build: one int-atomic pass (rank), two-level scan, atomic-free place.
// place packs labels[src] into csr.x (src<2^16, label<2^10); dinv[src] is
// applied in the agg inner loop (scalar/uniform load) -> no scale pass.
// out1 stored as fp16 -> layer-2 gather rows are 256B instead of 512B.
// ---------------------------------------------------------------------------

__global__ void init_kernel(int* __restrict__ cnt, int n) {
  int i = blockIdx.x * blockDim.x + threadIdx.x;
  if (i < n) cnt[i] = 0;
}

// rank[i] = arrival index of edge i within its dst row; cnt -> histogram.
__global__ void rank_kernel(const int* __restrict__ dst, int* __restrict__ cnt,
                            int* __restrict__ rank, int e) {
  int i = blockIdx.x * blockDim.x + threadIdx.x;
  if (i < e) rank[i] = atomicAdd(&cnt[dst[i]], 1);
}

// --- two-level exclusive scan of cnt[n] -> rs[n+1] ---
__global__ __launch_bounds__(256) void scan_a(const int* __restrict__ cnt,
                                              int* __restrict__ rs,
                                              int* __restrict__ bsum, int n) {
  __shared__ int wsum[4];
  int t = threadIdx.x, i = blockIdx.x * 256 + t;
  int lane = t & 63, wv = t >> 6;
  int v = (i < n) ? cnt[i] : 0;
  int x = v;
#pragma unroll
  for (int d = 1; d < 64; d <<= 1) {
    int tt = __shfl_up(x, d, 64);
    if (lane >= d) x += tt;
  }
  if (lane == 63) wsum[wv] = x;
  __syncthreads();
  int off = 0;
#pragma unroll
  for (int w = 0; w < 4; ++w) off += (w < wv) ? wsum[w] : 0;
  int excl = x - v + off;
  if (i < n) rs[i] = excl;
  if (t == 255) bsum[blockIdx.x] = excl + v;
}

__global__ __launch_bounds__(256) void scan_b(int* __restrict__ bsum, int nb) {
  __shared__ int wsum[4];
  int t = threadIdx.x;
  int lane = t & 63, wv = t >> 6;
  int v = (t < nb) ? bsum[t] : 0;
  int x = v;
#pragma unroll
  for (int d = 1; d < 64; d <<= 1) {
    int tt = __shfl_up(x, d, 64);
    if (lane >= d) x += tt;
  }
  if (lane == 63) wsum[wv] = x;
  __syncthreads();
  int off = 0;
#pragma unroll
  for (int w = 0; w < 4; ++w) off += (w < wv) ? wsum[w] : 0;
  if (t < nb) bsum[t] = x - v + off;
}

__global__ void scan_c(const int* __restrict__ bsum, int* __restrict__ rs,
                       int n, int e) {
  int i = blockIdx.x * blockDim.x + threadIdx.x;
  if (i < n) rs[i] += bsum[i >> 8];
  if (i == 0) rs[n] = e;
}

// place edge i at rs[dst]+rank[i]; csr = {src | label(src)<<16, w_bits}.
__global__ void place_kernel(const int* __restrict__ src, const int* __restrict__ dst,
                             const float* __restrict__ w, const int* __restrict__ rank,
                             const int* __restrict__ rs, const int* __restrict__ labels,
                             int2* __restrict__ csr, int e) {
  int i = blockIdx.x * blockDim.x + threadIdx.x;
  if (i < e) {
    int s = src[i];
    int pos = rs[dst[i]] + rank[i];
    csr[pos] = make_int2(s | (labels[s] << 16), __float_as_int(w[i]));
  }
}

// dinv[d] = rsqrt(1 + sum_w over row d)  (contiguous reads, wave per node)
__global__ __launch_bounds__(256) void deg_kernel(const int* __restrict__ rs,
                                                  const int2* __restrict__ csr,
                                                  float* __restrict__ dinv, int n) {
  int wid = (blockIdx.x * blockDim.x + threadIdx.x) >> 6;
  int lane = threadIdx.x & 63;
  if (wid >= n) return;
  int r0 = rs[wid], r1 = rs[wid + 1];
  float s = 0.f;
  for (int i = r0 + lane; i < r1; i += 64) s += __int_as_float(csr[i].y);
#pragma unroll
  for (int d = 1; d < 64; d <<= 1) s += __shfl_xor(s, d, 64);
  if (lane == 0) dinv[wid] = rsqrtf(1.0f + s);
}

// temb = emb_table @ W1   (vocab x 128 f32) -- tiny GEMM, L2-resident result
__global__ void temb_kernel(const float* __restrict__ emb, const float* __restrict__ W1,
                            float* __restrict__ temb) {
  int r = blockIdx.x, j = threadIdx.x;
  __shared__ float xs[128];
  xs[j] = emb[r * 128 + j];
  __syncthreads();
  float acc = 0.f;
#pragma unroll 8
  for (int k = 0; k < 128; ++k) acc = fmaf(xs[k], W1[k * 128 + j], acc);
  temb[r * 128 + j] = acc;
}

// Layer 1: out1 = relu(A_hat temb[labels] + b1), fp16 output.
// One wave per node; lane owns features [2*lane, 2*lane+1]. Edge metadata
// read at wave-uniform addresses (scalar-load friendly), no shfl.
__global__ __launch_bounds__(256) void agg1_kernel(
    const int* __restrict__ rs, const int2* __restrict__ csr,
    const float* __restrict__ dinv, const int* __restrict__ labels,
    const float* __restrict__ temb, const float* __restrict__ b1,
    __half2* __restrict__ out1, int n) {
  int wid = (blockIdx.x * blockDim.x + threadIdx.x) >> 6;
  int lane = threadIdx.x & 63;
  if (wid >= n) return;
  float di = dinv[wid];
  int selfrow = labels[wid];
  float2 hv = *(const float2*)(temb + (size_t)selfrow * 128 + 2 * lane);
  float acc0 = hv.x * di, acc1 = hv.y * di;  // self term (x di again at end)
  int r1v = rs[wid + 1];
  for (int i = rs[wid]; i < r1v; ++i) {
    int2 c = csr[i];
    float vj = __int_as_float(c.y) * dinv[c.x & 0xffff];
    const float2 hs = *(const float2*)(temb + (size_t)(c.x >> 16) * 128 + 2 * lane);
    acc0 = fmaf(hs.x, vj, acc0);
    acc1 = fmaf(hs.y, vj, acc1);
  }
  acc0 = fmaf(acc0, di, b1[2 * lane]);
  acc1 = fmaf(acc1, di, b1[2 * lane + 1]);
  out1[(size_t)wid * 64 + lane] =
      __float22half2_rn(make_float2(fmaxf(acc0, 0.f), fmaxf(acc1, 0.f)));
}

// Layer 2 aggregation: out = A_hat h (fp16 gather source, f32 output).
__global__ __launch_bounds__(256) void agg2_kernel(
    const int* __restrict__ rs, const int2* __restrict__ csr,
    const float* __restrict__ dinv, const __half2* __restrict__ h,
    float* __restrict__ out, int n) {
  int wid = (blockIdx.x * blockDim.x + threadIdx.x) >> 6;
  int lane = threadIdx.x & 63;
  if (wid >= n) return;
  float di = dinv[wid];
  float2 hv = __half22float2(h[(size_t)wid * 64 + lane]);
  float acc0 = hv.x * di, acc1 = hv.y * di;
  int r1v = rs[wid + 1];
  for (int i = rs[wid]; i < r1v; ++i) {
    int2 c = csr[i];
    int node = c.x & 0xffff;
    float vj = __int_as_float(c.y) * dinv[node];
    float2 hs = __half22float2(h[(size_t)node * 64 + lane]);
    acc0 = fmaf(hs.x, vj, acc0);
    acc1 = fmaf(hs.y, vj, acc1);
  }
  *(float2*)(out + (size_t)wid * 128 + 2 * lane) = make_float2(acc0 * di, acc1 * di);
}

// In-place: y[rb..rb+31] = y[rb..rb+31] @ W + b. Each block only touches its
// own 32 rows (staged to LDS before overwrite) -> in-place safe.
__global__ __launch_bounds__(256) void gemm_bias_kernel(float* __restrict__ y,
                                                        const float* __restrict__ W,
                                                        const float* __restrict__ bias,
                                                        int n) {
  __shared__ float xs[32][128];
  int tid = threadIdx.x;
  int tc = tid & 31;
  int tr = tid >> 5;
  int rb = blockIdx.x * 32;
  {
    const float4* xg = (const float4*)(y + (size_t)rb * 128);
    float4* xls = (float4*)&xs[0][0];
#pragma unroll
    for (int i = 0; i < 4; ++i) {
      int idx = tid + i * 256;  // float4 index; row = idx>>5
      int row = rb + (idx >> 5);
      float4 val = (row < n) ? xg[idx] : make_float4(0.f, 0.f, 0.f, 0.f);
      xls[idx] = val;
    }
  }
  __syncthreads();
  int j0 = tc * 4;
  float4 b4 = *(const float4*)(bias + j0);
  float acc[4][4];
#pragma unroll
  for (int r = 0; r < 4; ++r) {
    acc[r][0] = b4.x; acc[r][1] = b4.y; acc[r][2] = b4.z; acc[r][3] = b4.w;
  }
#pragma unroll 4
  for (int k = 0; k < 128; ++k) {
    float4 w4 = *(const float4*)(W + k * 128 + j0);
#pragma unroll
    for (int r = 0; r < 4; ++r) {
      float xv = xs[tr * 4 + r][k];
      acc[r][0] = fmaf(xv, w4.x, acc[r][0]);
      acc[r][1] = fmaf(xv, w4.y, acc[r][1]);
      acc[r][2] = fmaf(xv, w4.z, acc[r][2]);
      acc[r][3] = fmaf(xv, w4.w, acc[r][3]);
    }
  }
#pragma unroll
  for (int r = 0; r < 4; ++r) {
    int row = rb + tr * 4 + r;
    if (row < n)
      *(float4*)(y + (size_t)row * 128 + j0) =
          make_float4(acc[r][0], acc[r][1], acc[r][2], acc[r][3]);
  }
}

extern "C" void kernel_launch(void* const* d_in, const int* in_sizes, int n_in,
                              void* d_out, int out_size, void* d_ws, size_t ws_size,
                              hipStream_t stream) {
  const int* labels = (const int*)d_in[0];
  const int* edge_index = (const int*)d_in[1];
  const float* weight = (const float*)d_in[2];
  const float* emb = (const float*)d_in[3];
  const float* W1 = (const float*)d_in[4];
  const float* b1 = (const float*)d_in[5];
  const float* W2 = (const float*)d_in[6];
  const float* b2 = (const float*)d_in[7];

  int n = in_sizes[0];
  int e = in_sizes[1] / 2;
  int vocab = in_sizes[3] / 128;
  const int* srcp = edge_index;
  const int* dstp = edge_index + e;

  // workspace carve-up (float elements, 256-aligned). Total ~33 MiB.
  float* ws = (float*)d_ws;
  size_t o = 0;
  auto alloc_f = [&](size_t c) { float* p = ws + o; o += (c + 255) & ~(size_t)255; return p; };
  int*     cnt  = (int*)alloc_f(n);
  int*     rank = (int*)alloc_f(e);
  int*     rs   = (int*)alloc_f(n + 1);
  int*     bsum = (int*)alloc_f(256);
  int2*    csr  = (int2*)alloc_f((size_t)e * 2);
  float*   dinv = alloc_f(n);
  float*   temb = alloc_f((size_t)vocab * 128);
  __half2* out1 = (__half2*)alloc_f((size_t)n * 64);  // n*128 halves
  (void)ws_size;

  dim3 b256(256);
  int gn = (n + 255) / 256;
  int ge = (e + 255) / 256;
  int nb = gn;  // scan blocks (196 for n=50000)
  int gagg = (int)(((size_t)n * 64 + 255) / 256);

  init_kernel<<<gn, b256, 0, stream>>>(cnt, n);
  rank_kernel<<<ge, b256, 0, stream>>>(dstp, cnt, rank, e);
  scan_a<<<nb, b256, 0, stream>>>(cnt, rs, bsum, n);
  scan_b<<<1, b256, 0, stream>>>(bsum, nb);
  scan_c<<<gn, b256, 0, stream>>>(bsum, rs, n, e);
  place_kernel<<<ge, b256, 0, stream>>>(srcp, dstp, weight, rank, rs, labels, csr, e);
  deg_kernel<<<gagg, b256, 0, stream>>>(rs, csr, dinv, n);
  temb_kernel<<<vocab, 128, 0, stream>>>(emb, W1, temb);
  // layer 1: out1 = relu(A_hat temb[labels] + b1)  (fp16 out)
  agg1_kernel<<<gagg, b256, 0, stream>>>(rs, csr, dinv, labels, temb, b1, out1, n);
  // layer 2: d_out = (A_hat out1) @ W2 + b2   (agg first, then in-place GEMM)
  agg2_kernel<<<gagg, b256, 0, stream>>>(rs, csr, dinv, out1, (float*)d_out, n);
  gemm_bias_kernel<<<(n + 31) / 32, b256, 0, stream>>>((float*)d_out, W2, b2, n);
}

// Round 4
// 280.516 us; speedup vs baseline: 1.5241x; 1.5241x over previous
//
#include <hip/hip_runtime.h>
#include <hip/hip_fp16.h>

// ---------------------------------------------------------------------------
// 2-layer GCN on MI355X.
//   GCNConv(x) = A_hat (x W) + b = (A_hat x) W + b  (agg and linear commute),
//   and emb[labels]@W1 = (emb@W1)[labels] -> layer 1 gathers from a 512KB
//   L2-resident table; layer 2 aggregates first, then in-place GEMM on d_out.
// CSR build: one int-atomic pass (rank), two-level scan, atomic-free place.
// csr.x packs src | labels[src]<<16; csr.y is prescaled by dinv[src] in a
// separate streaming pass (keeps the agg inner loop memory-op-free per edge
// except the row gather itself).
// Agg inner loop: batch-load 64 edge records coalesced, then shfl-broadcast
// -> gather addresses come from registers -> deep memory-level parallelism.
// out1 stored fp16 -> layer-2 gather rows are 256B.
// ---------------------------------------------------------------------------

__global__ void init_kernel(int* __restrict__ cnt, int n) {
  int i = blockIdx.x * blockDim.x + threadIdx.x;
  if (i < n) cnt[i] = 0;
}

// rank[i] = arrival index of edge i within its dst row; cnt -> histogram.
__global__ void rank_kernel(const int* __restrict__ dst, int* __restrict__ cnt,
                            int* __restrict__ rank, int e) {
  int i = blockIdx.x * blockDim.x + threadIdx.x;
  if (i < e) rank[i] = atomicAdd(&cnt[dst[i]], 1);
}

// --- two-level exclusive scan of cnt[n] -> rs[n+1] ---
__global__ __launch_bounds__(256) void scan_a(const int* __restrict__ cnt,
                                              int* __restrict__ rs,
                                              int* __restrict__ bsum, int n) {
  __shared__ int wsum[4];
  int t = threadIdx.x, i = blockIdx.x * 256 + t;
  int lane = t & 63, wv = t >> 6;
  int v = (i < n) ? cnt[i] : 0;
  int x = v;
#pragma unroll
  for (int d = 1; d < 64; d <<= 1) {
    int tt = __shfl_up(x, d, 64);
    if (lane >= d) x += tt;
  }
  if (lane == 63) wsum[wv] = x;
  __syncthreads();
  int off = 0;
#pragma unroll
  for (int w = 0; w < 4; ++w) off += (w < wv) ? wsum[w] : 0;
  int excl = x - v + off;
  if (i < n) rs[i] = excl;
  if (t == 255) bsum[blockIdx.x] = excl + v;
}

__global__ __launch_bounds__(256) void scan_b(int* __restrict__ bsum, int nb) {
  __shared__ int wsum[4];
  int t = threadIdx.x;
  int lane = t & 63, wv = t >> 6;
  int v = (t < nb) ? bsum[t] : 0;
  int x = v;
#pragma unroll
  for (int d = 1; d < 64; d <<= 1) {
    int tt = __shfl_up(x, d, 64);
    if (lane >= d) x += tt;
  }
  if (lane == 63) wsum[wv] = x;
  __syncthreads();
  int off = 0;
#pragma unroll
  for (int w = 0; w < 4; ++w) off += (w < wv) ? wsum[w] : 0;
  if (t < nb) bsum[t] = x - v + off;
}

__global__ void scan_c(const int* __restrict__ bsum, int* __restrict__ rs,
                       int n, int e) {
  int i = blockIdx.x * blockDim.x + threadIdx.x;
  if (i < n) rs[i] += bsum[i >> 8];
  if (i == 0) rs[n] = e;
}

// place edge i at rs[dst]+rank[i]; csr = {src | label(src)<<16, w_bits}.
__global__ void place_kernel(const int* __restrict__ src, const int* __restrict__ dst,
                             const float* __restrict__ w, const int* __restrict__ rank,
                             const int* __restrict__ rs, const int* __restrict__ labels,
                             int2* __restrict__ csr, int e) {
  int i = blockIdx.x * blockDim.x + threadIdx.x;
  if (i < e) {
    int s = src[i];
    int pos = rs[dst[i]] + rank[i];
    csr[pos] = make_int2(s | (labels[s] << 16), __float_as_int(w[i]));
  }
}

// dinv[d] = rsqrt(1 + sum_w over row d)  (contiguous reads, wave per node)
// Runs BEFORE scale_kernel (csr.y still raw weights here).
__global__ __launch_bounds__(256) void deg_kernel(const int* __restrict__ rs,
                                                  const int2* __restrict__ csr,
                                                  float* __restrict__ dinv, int n) {
  int wid = (blockIdx.x * blockDim.x + threadIdx.x) >> 6;
  int lane = threadIdx.x & 63;
  if (wid >= n) return;
  int r0 = rs[wid], r1 = rs[wid + 1];
  float s = 0.f;
  for (int i = r0 + lane; i < r1; i += 64) s += __int_as_float(csr[i].y);
#pragma unroll
  for (int d = 1; d < 64; d <<= 1) s += __shfl_xor(s, d, 64);
  if (lane == 0) dinv[wid] = rsqrtf(1.0f + s);
}

// csr.y *= dinv[src]  (prescale; dinv[dst] applied per node in agg)
__global__ void scale_kernel(int2* __restrict__ csr, const float* __restrict__ dinv, int e) {
  int i = blockIdx.x * blockDim.x + threadIdx.x;
  if (i < e) {
    int2 c = csr[i];
    c.y = __float_as_int(__int_as_float(c.y) * dinv[c.x & 0xffff]);
    csr[i] = c;
  }
}

// temb = emb_table @ W1   (vocab x 128 f32) -- tiny GEMM, L2-resident result
__global__ void temb_kernel(const float* __restrict__ emb, const float* __restrict__ W1,
                            float* __restrict__ temb) {
  int r = blockIdx.x, j = threadIdx.x;
  __shared__ float xs[128];
  xs[j] = emb[r * 128 + j];
  __syncthreads();
  float acc = 0.f;
#pragma unroll 8
  for (int k = 0; k < 128; ++k) acc = fmaf(xs[k], W1[k * 128 + j], acc);
  temb[r * 128 + j] = acc;
}

// Layer 1: out1 = relu(A_hat temb[labels] + b1), fp16 output.
// One wave per node; lane owns features [2*lane, 2*lane+1].
__global__ __launch_bounds__(256) void agg1_kernel(
    const int* __restrict__ rs, const int2* __restrict__ csr,
    const float* __restrict__ dinv, const int* __restrict__ labels,
    const float* __restrict__ temb, const float* __restrict__ b1,
    __half2* __restrict__ out1, int n) {
  int wid = (blockIdx.x * blockDim.x + threadIdx.x) >> 6;
  int lane = threadIdx.x & 63;
  if (wid >= n) return;
  float di = dinv[wid];
  int selfrow = labels[wid];
  float2 hv = *(const float2*)(temb + (size_t)selfrow * 128 + 2 * lane);
  float acc0 = hv.x * di, acc1 = hv.y * di;  // self term (x di again at end)
  int r1v = rs[wid + 1];
  for (int base = rs[wid]; base < r1v; base += 64) {
    int s = 0;
    float v = 0.f;
    if (base + lane < r1v) {
      int2 c = csr[base + lane];
      s = c.x;
      v = __int_as_float(c.y);
    }
    int nb = min(64, r1v - base);
    int j = 0;
    for (; j + 8 <= nb; j += 8) {
#pragma unroll
      for (int u = 0; u < 8; ++u) {
        int sj = __shfl(s, j + u, 64);
        float vj = __shfl(v, j + u, 64);
        const float2 hs = *(const float2*)(temb + (size_t)(sj >> 16) * 128 + 2 * lane);
        acc0 = fmaf(hs.x, vj, acc0);
        acc1 = fmaf(hs.y, vj, acc1);
      }
    }
    for (; j < nb; ++j) {
      int sj = __shfl(s, j, 64);
      float vj = __shfl(v, j, 64);
      const float2 hs = *(const float2*)(temb + (size_t)(sj >> 16) * 128 + 2 * lane);
      acc0 = fmaf(hs.x, vj, acc0);
      acc1 = fmaf(hs.y, vj, acc1);
    }
  }
  acc0 = fmaf(acc0, di, b1[2 * lane]);
  acc1 = fmaf(acc1, di, b1[2 * lane + 1]);
  out1[(size_t)wid * 64 + lane] =
      __float22half2_rn(make_float2(fmaxf(acc0, 0.f), fmaxf(acc1, 0.f)));
}

// Layer 2 aggregation: out = A_hat h (fp16 gather source, f32 output).
__global__ __launch_bounds__(256) void agg2_kernel(
    const int* __restrict__ rs, const int2* __restrict__ csr,
    const float* __restrict__ dinv, const __half2* __restrict__ h,
    float* __restrict__ out, int n) {
  int wid = (blockIdx.x * blockDim.x + threadIdx.x) >> 6;
  int lane = threadIdx.x & 63;
  if (wid >= n) return;
  float di = dinv[wid];
  float2 hv = __half22float2(h[(size_t)wid * 64 + lane]);
  float acc0 = hv.x * di, acc1 = hv.y * di;
  int r1v = rs[wid + 1];
  for (int base = rs[wid]; base < r1v; base += 64) {
    int s = 0;
    float v = 0.f;
    if (base + lane < r1v) {
      int2 c = csr[base + lane];
      s = c.x;
      v = __int_as_float(c.y);
    }
    int nb = min(64, r1v - base);
    int j = 0;
    for (; j + 8 <= nb; j += 8) {
#pragma unroll
      for (int u = 0; u < 8; ++u) {
        int sj = __shfl(s, j + u, 64);
        float vj = __shfl(v, j + u, 64);
        float2 hs = __half22float2(h[(size_t)(sj & 0xffff) * 64 + lane]);
        acc0 = fmaf(hs.x, vj, acc0);
        acc1 = fmaf(hs.y, vj, acc1);
      }
    }
    for (; j < nb; ++j) {
      int sj = __shfl(s, j, 64);
      float vj = __shfl(v, j, 64);
      float2 hs = __half22float2(h[(size_t)(sj & 0xffff) * 64 + lane]);
      acc0 = fmaf(hs.x, vj, acc0);
      acc1 = fmaf(hs.y, vj, acc1);
    }
  }
  *(float2*)(out + (size_t)wid * 128 + 2 * lane) = make_float2(acc0 * di, acc1 * di);
}

// In-place: y[rb..rb+31] = y[rb..rb+31] @ W + b. Each block only touches its
// own 32 rows (staged to LDS before overwrite) -> in-place safe.
__global__ __launch_bounds__(256) void gemm_bias_kernel(float* __restrict__ y,
                                                        const float* __restrict__ W,
                                                        const float* __restrict__ bias,
                                                        int n) {
  __shared__ float xs[32][128];
  int tid = threadIdx.x;
  int tc = tid & 31;
  int tr = tid >> 5;
  int rb = blockIdx.x * 32;
  {
    const float4* xg = (const float4*)(y + (size_t)rb * 128);
    float4* xls = (float4*)&xs[0][0];
#pragma unroll
    for (int i = 0; i < 4; ++i) {
      int idx = tid + i * 256;  // float4 index; row = idx>>5
      int row = rb + (idx >> 5);
      float4 val = (row < n) ? xg[idx] : make_float4(0.f, 0.f, 0.f, 0.f);
      xls[idx] = val;
    }
  }
  __syncthreads();
  int j0 = tc * 4;
  float4 b4 = *(const float4*)(bias + j0);
  float acc[4][4];
#pragma unroll
  for (int r = 0; r < 4; ++r) {
    acc[r][0] = b4.x; acc[r][1] = b4.y; acc[r][2] = b4.z; acc[r][3] = b4.w;
  }
#pragma unroll 4
  for (int k = 0; k < 128; ++k) {
    float4 w4 = *(const float4*)(W + k * 128 + j0);
#pragma unroll
    for (int r = 0; r < 4; ++r) {
      float xv = xs[tr * 4 + r][k];
      acc[r][0] = fmaf(xv, w4.x, acc[r][0]);
      acc[r][1] = fmaf(xv, w4.y, acc[r][1]);
      acc[r][2] = fmaf(xv, w4.z, acc[r][2]);
      acc[r][3] = fmaf(xv, w4.w, acc[r][3]);
    }
  }
#pragma unroll
  for (int r = 0; r < 4; ++r) {
    int row = rb + tr * 4 + r;
    if (row < n)
      *(float4*)(y + (size_t)row * 128 + j0) =
          make_float4(acc[r][0], acc[r][1], acc[r][2], acc[r][3]);
  }
}

extern "C" void kernel_launch(void* const* d_in, const int* in_sizes, int n_in,
                              void* d_out, int out_size, void* d_ws, size_t ws_size,
                              hipStream_t stream) {
  const int* labels = (const int*)d_in[0];
  const int* edge_index = (const int*)d_in[1];
  const float* weight = (const float*)d_in[2];
  const float* emb = (const float*)d_in[3];
  const float* W1 = (const float*)d_in[4];
  const float* b1 = (const float*)d_in[5];
  const float* W2 = (const float*)d_in[6];
  const float* b2 = (const float*)d_in[7];

  int n = in_sizes[0];
  int e = in_sizes[1] / 2;
  int vocab = in_sizes[3] / 128;
  const int* srcp = edge_index;
  const int* dstp = edge_index + e;

  // workspace carve-up (float elements, 256-aligned). Total ~33 MiB.
  float* ws = (float*)d_ws;
  size_t o = 0;
  auto alloc_f = [&](size_t c) { float* p = ws + o; o += (c + 255) & ~(size_t)255; return p; };
  int*     cnt  = (int*)alloc_f(n);
  int*     rank = (int*)alloc_f(e);
  int*     rs   = (int*)alloc_f(n + 1);
  int*     bsum = (int*)alloc_f(256);
  int2*    csr  = (int2*)alloc_f((size_t)e * 2);
  float*   dinv = alloc_f(n);
  float*   temb = alloc_f((size_t)vocab * 128);
  __half2* out1 = (__half2*)alloc_f((size_t)n * 64);  // n*128 halves
  (void)ws_size;

  dim3 b256(256);
  int gn = (n + 255) / 256;
  int ge = (e + 255) / 256;
  int nb = gn;  // scan blocks (196 for n=50000)
  int gagg = (int)(((size_t)n * 64 + 255) / 256);

  init_kernel<<<gn, b256, 0, stream>>>(cnt, n);
  rank_kernel<<<ge, b256, 0, stream>>>(dstp, cnt, rank, e);
  scan_a<<<nb, b256, 0, stream>>>(cnt, rs, bsum, n);
  scan_b<<<1, b256, 0, stream>>>(bsum, nb);
  scan_c<<<gn, b256, 0, stream>>>(bsum, rs, n, e);
  place_kernel<<<ge, b256, 0, stream>>>(srcp, dstp, weight, rank, rs, labels, csr, e);
  deg_kernel<<<gagg, b256, 0, stream>>>(rs, csr, dinv, n);
  scale_kernel<<<ge, b256, 0, stream>>>(csr, dinv, e);
  temb_kernel<<<vocab, 128, 0, stream>>>(emb, W1, temb);
  // layer 1: out1 = relu(A_hat temb[labels] + b1)  (fp16 out)
  agg1_kernel<<<gagg, b256, 0, stream>>>(rs, csr, dinv, labels, temb, b1, out1, n);
  // layer 2: d_out = (A_hat out1) @ W2 + b2   (agg first, then in-place GEMM)
  agg2_kernel<<<gagg, b256, 0, stream>>>(rs, csr, dinv, out1, (float*)d_out, n);
  gemm_bias_kernel<<<(n + 31) / 32, b256, 0, stream>>>((float*)d_out, W2, b2, n);
}

// Round 5
// 271.137 us; speedup vs baseline: 1.5769x; 1.0346x over previous
//
#include <hip/hip_runtime.h>
#include <hip/hip_fp16.h>

// ---------------------------------------------------------------------------
// 2-layer GCN on MI355X.
//   GCNConv(x) = A_hat (x W) + b = (A_hat x) W + b  (agg and linear commute),
//   and emb[labels]@W1 = (emb@W1)[labels] -> layer 1 gathers from a 256KB
//   fp16 L2-resident table; layer 2 aggregates first, then in-place GEMM.
// CSR build: one int-atomic pass (rank; 8 edges/thread so 8 atomics are in
// flight per lane -- the pass is outstanding-atomic bound, not BW bound),
// two-level scan, atomic-free place (4 edges/thread for gather/store ILP).
// csr.x packs src | labels[src]<<16; csr.y prescaled by dinv[src].
// Agg inner loop: batch-load 64 edge records coalesced, shfl-broadcast ->
// gather addresses come from registers -> deep memory-level parallelism.
// out1 and temb stored fp16 -> gather rows are 256B.
// ---------------------------------------------------------------------------

__global__ void init_kernel(int* __restrict__ cnt, int n) {
  int i = blockIdx.x * blockDim.x + threadIdx.x;
  if (i < n) cnt[i] = 0;
}

// rank[i] = arrival index of edge i within its dst row; cnt -> histogram.
// 8 edges/thread, block-strided: coalesced loads, 8 independent atomics/lane.
__global__ __launch_bounds__(256) void rank_kernel(const int* __restrict__ dst,
                                                   int* __restrict__ cnt,
                                                   int* __restrict__ rank, int e) {
  int t = blockIdx.x * 2048 + threadIdx.x;
  int d[8], r[8];
#pragma unroll
  for (int u = 0; u < 8; ++u) {
    int i = t + u * 256;
    d[u] = (i < e) ? dst[i] : -1;
  }
#pragma unroll
  for (int u = 0; u < 8; ++u) r[u] = (d[u] >= 0) ? atomicAdd(&cnt[d[u]], 1) : 0;
#pragma unroll
  for (int u = 0; u < 8; ++u) {
    int i = t + u * 256;
    if (i < e) rank[i] = r[u];
  }
}

// --- two-level exclusive scan of cnt[n] -> rs[n+1] ---
__global__ __launch_bounds__(256) void scan_a(const int* __restrict__ cnt,
                                              int* __restrict__ rs,
                                              int* __restrict__ bsum, int n) {
  __shared__ int wsum[4];
  int t = threadIdx.x, i = blockIdx.x * 256 + t;
  int lane = t & 63, wv = t >> 6;
  int v = (i < n) ? cnt[i] : 0;
  int x = v;
#pragma unroll
  for (int d = 1; d < 64; d <<= 1) {
    int tt = __shfl_up(x, d, 64);
    if (lane >= d) x += tt;
  }
  if (lane == 63) wsum[wv] = x;
  __syncthreads();
  int off = 0;
#pragma unroll
  for (int w = 0; w < 4; ++w) off += (w < wv) ? wsum[w] : 0;
  int excl = x - v + off;
  if (i < n) rs[i] = excl;
  if (t == 255) bsum[blockIdx.x] = excl + v;
}

__global__ __launch_bounds__(256) void scan_b(int* __restrict__ bsum, int nb) {
  __shared__ int wsum[4];
  int t = threadIdx.x;
  int lane = t & 63, wv = t >> 6;
  int v = (t < nb) ? bsum[t] : 0;
  int x = v;
#pragma unroll
  for (int d = 1; d < 64; d <<= 1) {
    int tt = __shfl_up(x, d, 64);
    if (lane >= d) x += tt;
  }
  if (lane == 63) wsum[wv] = x;
  __syncthreads();
  int off = 0;
#pragma unroll
  for (int w = 0; w < 4; ++w) off += (w < wv) ? wsum[w] : 0;
  if (t < nb) bsum[t] = x - v + off;
}

__global__ void scan_c(const int* __restrict__ bsum, int* __restrict__ rs,
                       int n, int e) {
  int i = blockIdx.x * blockDim.x + threadIdx.x;
  if (i < n) rs[i] += bsum[i >> 8];
  if (i == 0) rs[n] = e;
}

// place edge i at rs[dst]+rank[i]; csr = {src | label(src)<<16, w_bits}.
// 4 edges/thread, staged loads -> 4 independent gathers + stores in flight.
__global__ __launch_bounds__(256) void place_kernel(
    const int* __restrict__ src, const int* __restrict__ dst,
    const float* __restrict__ w, const int* __restrict__ rank,
    const int* __restrict__ rs, const int* __restrict__ labels,
    int2* __restrict__ csr, int e) {
  int t = blockIdx.x * 1024 + threadIdx.x;
  int s[4], d[4], rk[4];
  float wv[4];
#pragma unroll
  for (int u = 0; u < 4; ++u) {
    int i = t + u * 256;
    bool ok = i < e;
    s[u] = ok ? src[i] : 0;
    d[u] = ok ? dst[i] : 0;
    rk[u] = ok ? rank[i] : 0;
    wv[u] = ok ? w[i] : 0.f;
  }
  int pos[4], lb[4];
#pragma unroll
  for (int u = 0; u < 4; ++u) pos[u] = rs[d[u]] + rk[u];
#pragma unroll
  for (int u = 0; u < 4; ++u) lb[u] = labels[s[u]];
#pragma unroll
  for (int u = 0; u < 4; ++u) {
    int i = t + u * 256;
    if (i < e) csr[pos[u]] = make_int2(s[u] | (lb[u] << 16), __float_as_int(wv[u]));
  }
}

// dinv[d] = rsqrt(1 + sum_w over row d)  (contiguous reads, wave per node)
// Runs BEFORE scale_kernel (csr.y still raw weights here).
__global__ __launch_bounds__(256) void deg_kernel(const int* __restrict__ rs,
                                                  const int2* __restrict__ csr,
                                                  float* __restrict__ dinv, int n) {
  int wid = (blockIdx.x * blockDim.x + threadIdx.x) >> 6;
  int lane = threadIdx.x & 63;
  if (wid >= n) return;
  int r0 = rs[wid], r1 = rs[wid + 1];
  float s = 0.f;
  for (int i = r0 + lane; i < r1; i += 64) s += __int_as_float(csr[i].y);
#pragma unroll
  for (int d = 1; d < 64; d <<= 1) s += __shfl_xor(s, d, 64);
  if (lane == 0) dinv[wid] = rsqrtf(1.0f + s);
}

// csr.y *= dinv[src]  (prescale; dinv[dst] applied per node in agg)
__global__ void scale_kernel(int2* __restrict__ csr, const float* __restrict__ dinv, int e) {
  int i = blockIdx.x * blockDim.x + threadIdx.x;
  if (i < e) {
    int2 c = csr[i];
    c.y = __float_as_int(__int_as_float(c.y) * dinv[c.x & 0xffff]);
    csr[i] = c;
  }
}

// temb = emb_table @ W1, stored fp16  (vocab x 128) -- 256KB L2-resident table
__global__ void temb_kernel(const float* __restrict__ emb, const float* __restrict__ W1,
                            __half* __restrict__ temb) {
  int r = blockIdx.x, j = threadIdx.x;
  __shared__ float xs[128];
  xs[j] = emb[r * 128 + j];
  __syncthreads();
  float acc = 0.f;
#pragma unroll 8
  for (int k = 0; k < 128; ++k) acc = fmaf(xs[k], W1[k * 128 + j], acc);
  temb[r * 128 + j] = __float2half_rn(acc);
}

// Layer 1: out1 = relu(A_hat temb[labels] + b1), fp16 in/out.
// One wave per node; lane owns features [2*lane, 2*lane+1].
__global__ __launch_bounds__(256) void agg1_kernel(
    const int* __restrict__ rs, const int2* __restrict__ csr,
    const float* __restrict__ dinv, const int* __restrict__ labels,
    const __half2* __restrict__ temb, const float* __restrict__ b1,
    __half2* __restrict__ out1, int n) {
  int wid = (blockIdx.x * blockDim.x + threadIdx.x) >> 6;
  int lane = threadIdx.x & 63;
  if (wid >= n) return;
  float di = dinv[wid];
  int selfrow = labels[wid];
  float2 hv = __half22float2(temb[(size_t)selfrow * 64 + lane]);
  float acc0 = hv.x * di, acc1 = hv.y * di;  // self term (x di again at end)
  int r1v = rs[wid + 1];
  for (int base = rs[wid]; base < r1v; base += 64) {
    int s = 0;
    float v = 0.f;
    if (base + lane < r1v) {
      int2 c = csr[base + lane];
      s = c.x;
      v = __int_as_float(c.y);
    }
    int nb = min(64, r1v - base);
    int j = 0;
    for (; j + 8 <= nb; j += 8) {
#pragma unroll
      for (int u = 0; u < 8; ++u) {
        int sj = __shfl(s, j + u, 64);
        float vj = __shfl(v, j + u, 64);
        float2 hs = __half22float2(temb[(size_t)(sj >> 16) * 64 + lane]);
        acc0 = fmaf(hs.x, vj, acc0);
        acc1 = fmaf(hs.y, vj, acc1);
      }
    }
    for (; j < nb; ++j) {
      int sj = __shfl(s, j, 64);
      float vj = __shfl(v, j, 64);
      float2 hs = __half22float2(temb[(size_t)(sj >> 16) * 64 + lane]);
      acc0 = fmaf(hs.x, vj, acc0);
      acc1 = fmaf(hs.y, vj, acc1);
    }
  }
  acc0 = fmaf(acc0, di, b1[2 * lane]);
  acc1 = fmaf(acc1, di, b1[2 * lane + 1]);
  out1[(size_t)wid * 64 + lane] =
      __float22half2_rn(make_float2(fmaxf(acc0, 0.f), fmaxf(acc1, 0.f)));
}

// Layer 2 aggregation: out = A_hat h (fp16 gather source, f32 output).
__global__ __launch_bounds__(256) void agg2_kernel(
    const int* __restrict__ rs, const int2* __restrict__ csr,
    const float* __restrict__ dinv, const __half2* __restrict__ h,
    float* __restrict__ out, int n) {
  int wid = (blockIdx.x * blockDim.x + threadIdx.x) >> 6;
  int lane = threadIdx.x & 63;
  if (wid >= n) return;
  float di = dinv[wid];
  float2 hv = __half22float2(h[(size_t)wid * 64 + lane]);
  float acc0 = hv.x * di, acc1 = hv.y * di;
  int r1v = rs[wid + 1];
  for (int base = rs[wid]; base < r1v; base += 64) {
    int s = 0;
    float v = 0.f;
    if (base + lane < r1v) {
      int2 c = csr[base + lane];
      s = c.x;
      v = __int_as_float(c.y);
    }
    int nb = min(64, r1v - base);
    int j = 0;
    for (; j + 8 <= nb; j += 8) {
#pragma unroll
      for (int u = 0; u < 8; ++u) {
        int sj = __shfl(s, j + u, 64);
        float vj = __shfl(v, j + u, 64);
        float2 hs = __half22float2(h[(size_t)(sj & 0xffff) * 64 + lane]);
        acc0 = fmaf(hs.x, vj, acc0);
        acc1 = fmaf(hs.y, vj, acc1);
      }
    }
    for (; j < nb; ++j) {
      int sj = __shfl(s, j, 64);
      float vj = __shfl(v, j, 64);
      float2 hs = __half22float2(h[(size_t)(sj & 0xffff) * 64 + lane]);
      acc0 = fmaf(hs.x, vj, acc0);
      acc1 = fmaf(hs.y, vj, acc1);
    }
  }
  *(float2*)(out + (size_t)wid * 128 + 2 * lane) = make_float2(acc0 * di, acc1 * di);
}

// In-place: y[rb..rb+31] = y[rb..rb+31] @ W + b. Each block only touches its
// own 32 rows (staged to LDS before overwrite) -> in-place safe.
__global__ __launch_bounds__(256) void gemm_bias_kernel(float* __restrict__ y,
                                                        const float* __restrict__ W,
                                                        const float* __restrict__ bias,
                                                        int n) {
  __shared__ float xs[32][128];
  int tid = threadIdx.x;
  int tc = tid & 31;
  int tr = tid >> 5;
  int rb = blockIdx.x * 32;
  {
    const float4* xg = (const float4*)(y + (size_t)rb * 128);
    float4* xls = (float4*)&xs[0][0];
#pragma unroll
    for (int i = 0; i < 4; ++i) {
      int idx = tid + i * 256;  // float4 index; row = idx>>5
      int row = rb + (idx >> 5);
      float4 val = (row < n) ? xg[idx] : make_float4(0.f, 0.f, 0.f, 0.f);
      xls[idx] = val;
    }
  }
  __syncthreads();
  int j0 = tc * 4;
  float4 b4 = *(const float4*)(bias + j0);
  float acc[4][4];
#pragma unroll
  for (int r = 0; r < 4; ++r) {
    acc[r][0] = b4.x; acc[r][1] = b4.y; acc[r][2] = b4.z; acc[r][3] = b4.w;
  }
#pragma unroll 4
  for (int k = 0; k < 128; ++k) {
    float4 w4 = *(const float4*)(W + k * 128 + j0);
#pragma unroll
    for (int r = 0; r < 4; ++r) {
      float xv = xs[tr * 4 + r][k];
      acc[r][0] = fmaf(xv, w4.x, acc[r][0]);
      acc[r][1] = fmaf(xv, w4.y, acc[r][1]);
      acc[r][2] = fmaf(xv, w4.z, acc[r][2]);
      acc[r][3] = fmaf(xv, w4.w, acc[r][3]);
    }
  }
#pragma unroll
  for (int r = 0; r < 4; ++r) {
    int row = rb + tr * 4 + r;
    if (row < n)
      *(float4*)(y + (size_t)row * 128 + j0) =
          make_float4(acc[r][0], acc[r][1], acc[r][2], acc[r][3]);
  }
}

extern "C" void kernel_launch(void* const* d_in, const int* in_sizes, int n_in,
                              void* d_out, int out_size, void* d_ws, size_t ws_size,
                              hipStream_t stream) {
  const int* labels = (const int*)d_in[0];
  const int* edge_index = (const int*)d_in[1];
  const float* weight = (const float*)d_in[2];
  const float* emb = (const float*)d_in[3];
  const float* W1 = (const float*)d_in[4];
  const float* b1 = (const float*)d_in[5];
  const float* W2 = (const float*)d_in[6];
  const float* b2 = (const float*)d_in[7];

  int n = in_sizes[0];
  int e = in_sizes[1] / 2;
  int vocab = in_sizes[3] / 128;
  const int* srcp = edge_index;
  const int* dstp = edge_index + e;

  // workspace carve-up (float elements, 256-aligned). Total ~33 MiB.
  float* ws = (float*)d_ws;
  size_t o = 0;
  auto alloc_f = [&](size_t c) { float* p = ws + o; o += (c + 255) & ~(size_t)255; return p; };
  int*     cnt  = (int*)alloc_f(n);
  int*     rank = (int*)alloc_f(e);
  int*     rs   = (int*)alloc_f(n + 1);
  int*     bsum = (int*)alloc_f(256);
  int2*    csr  = (int2*)alloc_f((size_t)e * 2);
  float*   dinv = alloc_f(n);
  __half*  temb = (__half*)alloc_f((size_t)vocab * 64);  // vocab*128 halves
  __half2* out1 = (__half2*)alloc_f((size_t)n * 64);     // n*128 halves
  (void)ws_size;

  dim3 b256(256);
  int gn = (n + 255) / 256;
  int ge = (e + 255) / 256;
  int nb = gn;  // scan blocks (196 for n=50000)
  int gagg = (int)(((size_t)n * 64 + 255) / 256);

  init_kernel<<<gn, b256, 0, stream>>>(cnt, n);
  rank_kernel<<<(e + 2047) / 2048, b256, 0, stream>>>(dstp, cnt, rank, e);
  scan_a<<<nb, b256, 0, stream>>>(cnt, rs, bsum, n);
  scan_b<<<1, b256, 0, stream>>>(bsum, nb);
  scan_c<<<gn, b256, 0, stream>>>(bsum, rs, n, e);
  place_kernel<<<(e + 1023) / 1024, b256, 0, stream>>>(srcp, dstp, weight, rank, rs,
                                                       labels, csr, e);
  deg_kernel<<<gagg, b256, 0, stream>>>(rs, csr, dinv, n);
  scale_kernel<<<ge, b256, 0, stream>>>(csr, dinv, e);
  temb_kernel<<<vocab, 128, 0, stream>>>(emb, W1, temb);
  // layer 1: out1 = relu(A_hat temb[labels] + b1)  (fp16 in/out)
  agg1_kernel<<<gagg, b256, 0, stream>>>(rs, csr, dinv, labels, (const __half2*)temb,
                                         b1, out1, n);
  // layer 2: d_out = (A_hat out1) @ W2 + b2   (agg first, then in-place GEMM)
  agg2_kernel<<<gagg, b256, 0, stream>>>(rs, csr, dinv, out1, (float*)d_out, n);
  gemm_bias_kernel<<<(n + 31) / 32, b256, 0, stream>>>((float*)d_out, W2, b2, n);
}

// Round 6
// 218.632 us; speedup vs baseline: 1.9556x; 1.2402x over previous
//
#include <hip/hip_runtime.h>
#include <hip/hip_fp16.h>

// ---------------------------------------------------------------------------
// 2-layer GCN on MI355X.
//   GCNConv(x) = A_hat (x W) + b = (A_hat x) W + b  (agg and linear commute),
//   and emb[labels]@W1 = (emb@W1)[labels] -> layer 1 gathers from a 256KB
//   fp16 L2-resident table; layer 2 aggregates first, then in-place GEMM.
// CSR build: ZERO global atomics (fabric atomic ceiling ~22G/s made the old
// rank pass a hard 74us floor). Two-level counting sort instead:
//   K1: per-chunk LDS histogram over 782 dst-buckets (bucket = dst>>6)
//   K2: per-bucket column scan over chunks (wave/bucket, shfl)
//   K2b: bucket-base scan (ebase)
//   K3: scatter into bucket-grouped records; rank via LDS atomic return
//   K4: per-bucket 64-bin sort -> final CSR (+ rs[]), same format as before
// Downstream (deg/scale/temb/agg1/agg2/gemm) unchanged & proven:
// csr.x packs src | labels[src]<<16; csr.y prescaled by dinv[src]; agg inner
// loop batch-loads 64 edge records, shfl-broadcasts -> deep gather MLP;
// out1 and temb fp16 -> 256B gather rows.
// ---------------------------------------------------------------------------

#define CHUNKS 896  // 14*64; chunk = ceil(e/896) = 1786 for e=1.6M (<=1792)

// K1: per-chunk histogram of dst-buckets (nb = ceil(n/64) <= 1024).
__global__ __launch_bounds__(256) void hist_kernel(const int* __restrict__ dst,
                                                   int* __restrict__ hist,
                                                   int e, int chunk, int nb) {
  __shared__ unsigned lh[1024];
  int b = blockIdx.x, t = threadIdx.x;
  int start = b * chunk, end = min(e, start + chunk);
  for (int i = t; i < nb; i += 256) lh[i] = 0;
  __syncthreads();
  for (int i = start + t; i < end; i += 256) atomicAdd(&lh[dst[i] >> 6], 1u);
  __syncthreads();
  for (int k = t; k < nb; k += 256) hist[(size_t)k * CHUNKS + b] = (int)lh[k];
}

// K2: one wave per bucket k: exclusive scan of hist[k][*] over chunks.
__global__ __launch_bounds__(256) void colscan_kernel(const int* __restrict__ hist,
                                                      int* __restrict__ off,
                                                      int* __restrict__ tot,
                                                      int nb, int bact) {
  int k = (blockIdx.x * 256 + threadIdx.x) >> 6;
  int lane = threadIdx.x & 63;
  if (k >= nb) return;
  int carry = 0;
  for (int r = 0; r < CHUNKS / 64; ++r) {
    int b = r * 64 + lane;
    int h = (b < bact) ? hist[(size_t)k * CHUNKS + b] : 0;
    int x = h;
#pragma unroll
    for (int d = 1; d < 64; d <<= 1) {
      int tt = __shfl_up(x, d, 64);
      if (lane >= d) x += tt;
    }
    if (b < bact) off[(size_t)k * CHUNKS + b] = carry + x - h;
    carry += __shfl(x, 63, 64);
  }
  if (lane == 0) tot[k] = carry;
}

// K2b: single block: exclusive scan of tot[nb] -> ebase[nb+1].
__global__ __launch_bounds__(1024) void ebase_kernel(const int* __restrict__ tot,
                                                     int* __restrict__ ebase, int nb) {
  __shared__ int wsum[16];
  int t = threadIdx.x, lane = t & 63, wv = t >> 6;
  int v = (t < nb) ? tot[t] : 0;
  int x = v;
#pragma unroll
  for (int d = 1; d < 64; d <<= 1) {
    int tt = __shfl_up(x, d, 64);
    if (lane >= d) x += tt;
  }
  if (lane == 63) wsum[wv] = x;
  __syncthreads();
  int o = 0;
#pragma unroll
  for (int w = 0; w < 16; ++w) o += (w < wv) ? wsum[w] : 0;
  int excl = x - v + o;
  if (t < nb) ebase[t] = excl;
  if (t == nb - 1) ebase[nb] = excl + v;
}

// K3: scatter edges into bucket-grouped records. Rank within (chunk,bucket)
// via LDS atomic return; pos = ebase[k] + off[k][b] + lrank. No global atomics.
// rec.x = src | dst_local<<16 | label<<22 (unsigned), rec.y = w bits.
__global__ __launch_bounds__(256) void scatter_kernel(
    const int* __restrict__ src, const int* __restrict__ dst,
    const float* __restrict__ w, const int* __restrict__ labels,
    const int* __restrict__ off, const int* __restrict__ ebase,
    int2* __restrict__ brec, int e, int chunk) {
  __shared__ unsigned bincnt[1024];
  int b = blockIdx.x, t = threadIdx.x;
  int start = b * chunk, end = min(e, start + chunk);
  for (int i = t; i < 1024; i += 256) bincnt[i] = 0;
  __syncthreads();
  int s[7], d[7], lb[7], bs[7];
  float wv[7];
#pragma unroll
  for (int u = 0; u < 7; ++u) {
    int i = start + u * 256 + t;
    bool ok = i < end;
    s[u] = ok ? src[i] : 0;
    d[u] = ok ? dst[i] : 0;
    wv[u] = ok ? w[i] : 0.f;
  }
#pragma unroll
  for (int u = 0; u < 7; ++u) lb[u] = labels[s[u]];
#pragma unroll
  for (int u = 0; u < 7; ++u) {
    int k = d[u] >> 6;
    bs[u] = ebase[k] + off[(size_t)k * CHUNKS + b];
  }
#pragma unroll
  for (int u = 0; u < 7; ++u) {
    int i = start + u * 256 + t;
    if (i < end) {
      int k = d[u] >> 6;
      unsigned lr = atomicAdd(&bincnt[k], 1u);
      unsigned rx = (unsigned)s[u] | ((unsigned)(d[u] & 63) << 16) |
                    ((unsigned)lb[u] << 22);
      brec[bs[u] + (int)lr] = make_int2((int)rx, __float_as_int(wv[u]));
    }
  }
}

// K4: per-bucket 64-bin sort: brec -> csr (src|label<<16, w), plus rs[].
__global__ __launch_bounds__(256) void bsort_kernel(const int2* __restrict__ brec,
                                                    const int* __restrict__ ebase,
                                                    int2* __restrict__ csr,
                                                    int* __restrict__ rs, int n) {
  __shared__ unsigned h64[64];
  __shared__ unsigned cur[64];
  int k = blockIdx.x, t = threadIdx.x;
  int e0 = ebase[k], e1 = ebase[k + 1];
  if (t < 64) h64[t] = 0;
  __syncthreads();
  for (int i = e0 + t; i < e1; i += 256)
    atomicAdd(&h64[((unsigned)brec[i].x >> 16) & 63u], 1u);
  __syncthreads();
  if (t < 64) {
    int hv = (int)h64[t];
    int x = hv;
#pragma unroll
    for (int d = 1; d < 64; d <<= 1) {
      int tt = __shfl_up(x, d, 64);
      if (t >= d) x += tt;
    }
    int ex = x - hv;
    cur[t] = (unsigned)(e0 + ex);
    int v = k * 64 + t;
    if (v <= n) rs[v] = e0 + ex;  // last bucket's lane localN writes rs[n]=e
  }
  __syncthreads();
  for (int i = e0 + t; i < e1; i += 256) {
    int2 r = brec[i];
    unsigned rx = (unsigned)r.x;
    int dl = (int)((rx >> 16) & 63u);
    int pos = (int)atomicAdd(&cur[dl], 1u);
    csr[pos] = make_int2((int)((rx & 0xffffu) | ((rx >> 22) << 16)), r.y);
  }
}

// dinv[d] = rsqrt(1 + sum_w over row d)  (contiguous reads, wave per node)
// Runs BEFORE scale_kernel (csr.y still raw weights here).
__global__ __launch_bounds__(256) void deg_kernel(const int* __restrict__ rs,
                                                  const int2* __restrict__ csr,
                                                  float* __restrict__ dinv, int n) {
  int wid = (blockIdx.x * blockDim.x + threadIdx.x) >> 6;
  int lane = threadIdx.x & 63;
  if (wid >= n) return;
  int r0 = rs[wid], r1 = rs[wid + 1];
  float s = 0.f;
  for (int i = r0 + lane; i < r1; i += 64) s += __int_as_float(csr[i].y);
#pragma unroll
  for (int d = 1; d < 64; d <<= 1) s += __shfl_xor(s, d, 64);
  if (lane == 0) dinv[wid] = rsqrtf(1.0f + s);
}

// csr.y *= dinv[src]  (prescale; dinv[dst] applied per node in agg)
__global__ void scale_kernel(int2* __restrict__ csr, const float* __restrict__ dinv, int e) {
  int i = blockIdx.x * blockDim.x + threadIdx.x;
  if (i < e) {
    int2 c = csr[i];
    c.y = __float_as_int(__int_as_float(c.y) * dinv[c.x & 0xffff]);
    csr[i] = c;
  }
}

// temb = emb_table @ W1, stored fp16  (vocab x 128) -- 256KB L2-resident table
__global__ void temb_kernel(const float* __restrict__ emb, const float* __restrict__ W1,
                            __half* __restrict__ temb) {
  int r = blockIdx.x, j = threadIdx.x;
  __shared__ float xs[128];
  xs[j] = emb[r * 128 + j];
  __syncthreads();
  float acc = 0.f;
#pragma unroll 8
  for (int k = 0; k < 128; ++k) acc = fmaf(xs[k], W1[k * 128 + j], acc);
  temb[r * 128 + j] = __float2half_rn(acc);
}

// Layer 1: out1 = relu(A_hat temb[labels] + b1), fp16 in/out.
// One wave per node; lane owns features [2*lane, 2*lane+1].
__global__ __launch_bounds__(256) void agg1_kernel(
    const int* __restrict__ rs, const int2* __restrict__ csr,
    const float* __restrict__ dinv, const int* __restrict__ labels,
    const __half2* __restrict__ temb, const float* __restrict__ b1,
    __half2* __restrict__ out1, int n) {
  int wid = (blockIdx.x * blockDim.x + threadIdx.x) >> 6;
  int lane = threadIdx.x & 63;
  if (wid >= n) return;
  float di = dinv[wid];
  int selfrow = labels[wid];
  float2 hv = __half22float2(temb[(size_t)selfrow * 64 + lane]);
  float acc0 = hv.x * di, acc1 = hv.y * di;  // self term (x di again at end)
  int r1v = rs[wid + 1];
  for (int base = rs[wid]; base < r1v; base += 64) {
    int s = 0;
    float v = 0.f;
    if (base + lane < r1v) {
      int2 c = csr[base + lane];
      s = c.x;
      v = __int_as_float(c.y);
    }
    int nb = min(64, r1v - base);
    int j = 0;
    for (; j + 8 <= nb; j += 8) {
#pragma unroll
      for (int u = 0; u < 8; ++u) {
        int sj = __shfl(s, j + u, 64);
        float vj = __shfl(v, j + u, 64);
        float2 hs = __half22float2(temb[(size_t)(sj >> 16) * 64 + lane]);
        acc0 = fmaf(hs.x, vj, acc0);
        acc1 = fmaf(hs.y, vj, acc1);
      }
    }
    for (; j < nb; ++j) {
      int sj = __shfl(s, j, 64);
      float vj = __shfl(v, j, 64);
      float2 hs = __half22float2(temb[(size_t)(sj >> 16) * 64 + lane]);
      acc0 = fmaf(hs.x, vj, acc0);
      acc1 = fmaf(hs.y, vj, acc1);
    }
  }
  acc0 = fmaf(acc0, di, b1[2 * lane]);
  acc1 = fmaf(acc1, di, b1[2 * lane + 1]);
  out1[(size_t)wid * 64 + lane] =
      __float22half2_rn(make_float2(fmaxf(acc0, 0.f), fmaxf(acc1, 0.f)));
}

// Layer 2 aggregation: out = A_hat h (fp16 gather source, f32 output).
__global__ __launch_bounds__(256) void agg2_kernel(
    const int* __restrict__ rs, const int2* __restrict__ csr,
    const float* __restrict__ dinv, const __half2* __restrict__ h,
    float* __restrict__ out, int n) {
  int wid = (blockIdx.x * blockDim.x + threadIdx.x) >> 6;
  int lane = threadIdx.x & 63;
  if (wid >= n) return;
  float di = dinv[wid];
  float2 hv = __half22float2(h[(size_t)wid * 64 + lane]);
  float acc0 = hv.x * di, acc1 = hv.y * di;
  int r1v = rs[wid + 1];
  for (int base = rs[wid]; base < r1v; base += 64) {
    int s = 0;
    float v = 0.f;
    if (base + lane < r1v) {
      int2 c = csr[base + lane];
      s = c.x;
      v = __int_as_float(c.y);
    }
    int nb = min(64, r1v - base);
    int j = 0;
    for (; j + 8 <= nb; j += 8) {
#pragma unroll
      for (int u = 0; u < 8; ++u) {
        int sj = __shfl(s, j + u, 64);
        float vj = __shfl(v, j + u, 64);
        float2 hs = __half22float2(h[(size_t)(sj & 0xffff) * 64 + lane]);
        acc0 = fmaf(hs.x, vj, acc0);
        acc1 = fmaf(hs.y, vj, acc1);
      }
    }
    for (; j < nb; ++j) {
      int sj = __shfl(s, j, 64);
      float vj = __shfl(v, j, 64);
      float2 hs = __half22float2(h[(size_t)(sj & 0xffff) * 64 + lane]);
      acc0 = fmaf(hs.x, vj, acc0);
      acc1 = fmaf(hs.y, vj, acc1);
    }
  }
  *(float2*)(out + (size_t)wid * 128 + 2 * lane) = make_float2(acc0 * di, acc1 * di);
}

// In-place: y[rb..rb+31] = y[rb..rb+31] @ W + b. Each block only touches its
// own 32 rows (staged to LDS before overwrite) -> in-place safe.
__global__ __launch_bounds__(256) void gemm_bias_kernel(float* __restrict__ y,
                                                        const float* __restrict__ W,
                                                        const float* __restrict__ bias,
                                                        int n) {
  __shared__ float xs[32][128];
  int tid = threadIdx.x;
  int tc = tid & 31;
  int tr = tid >> 5;
  int rb = blockIdx.x * 32;
  {
    const float4* xg = (const float4*)(y + (size_t)rb * 128);
    float4* xls = (float4*)&xs[0][0];
#pragma unroll
    for (int i = 0; i < 4; ++i) {
      int idx = tid + i * 256;  // float4 index; row = idx>>5
      int row = rb + (idx >> 5);
      float4 val = (row < n) ? xg[idx] : make_float4(0.f, 0.f, 0.f, 0.f);
      xls[idx] = val;
    }
  }
  __syncthreads();
  int j0 = tc * 4;
  float4 b4 = *(const float4*)(bias + j0);
  float acc[4][4];
#pragma unroll
  for (int r = 0; r < 4; ++r) {
    acc[r][0] = b4.x; acc[r][1] = b4.y; acc[r][2] = b4.z; acc[r][3] = b4.w;
  }
#pragma unroll 4
  for (int k = 0; k < 128; ++k) {
    float4 w4 = *(const float4*)(W + k * 128 + j0);
#pragma unroll
    for (int r = 0; r < 4; ++r) {
      float xv = xs[tr * 4 + r][k];
      acc[r][0] = fmaf(xv, w4.x, acc[r][0]);
      acc[r][1] = fmaf(xv, w4.y, acc[r][1]);
      acc[r][2] = fmaf(xv, w4.z, acc[r][2]);
      acc[r][3] = fmaf(xv, w4.w, acc[r][3]);
    }
  }
#pragma unroll
  for (int r = 0; r < 4; ++r) {
    int row = rb + tr * 4 + r;
    if (row < n)
      *(float4*)(y + (size_t)row * 128 + j0) =
          make_float4(acc[r][0], acc[r][1], acc[r][2], acc[r][3]);
  }
}

extern "C" void kernel_launch(void* const* d_in, const int* in_sizes, int n_in,
                              void* d_out, int out_size, void* d_ws, size_t ws_size,
                              hipStream_t stream) {
  const int* labels = (const int*)d_in[0];
  const int* edge_index = (const int*)d_in[1];
  const float* weight = (const float*)d_in[2];
  const float* emb = (const float*)d_in[3];
  const float* W1 = (const float*)d_in[4];
  const float* b1 = (const float*)d_in[5];
  const float* W2 = (const float*)d_in[6];
  const float* b2 = (const float*)d_in[7];

  int n = in_sizes[0];
  int e = in_sizes[1] / 2;
  int vocab = in_sizes[3] / 128;
  const int* srcp = edge_index;
  const int* dstp = edge_index + e;

  int nb = (n + 63) >> 6;                 // dst buckets (782)
  int chunk = (e + CHUNKS - 1) / CHUNKS;  // 1786 (<=1792 for unroll-7 staging)
  int bact = (e + chunk - 1) / chunk;     // actual chunks (<= CHUNKS)

  // workspace carve-up (float elements, 256-aligned). Total ~45 MiB.
  float* ws = (float*)d_ws;
  size_t o = 0;
  auto alloc_f = [&](size_t c) { float* p = ws + o; o += (c + 255) & ~(size_t)255; return p; };
  int*     hist  = (int*)alloc_f((size_t)nb * CHUNKS);
  int*     off   = (int*)alloc_f((size_t)nb * CHUNKS);
  int*     tot   = (int*)alloc_f(nb);
  int*     ebase = (int*)alloc_f(nb + 1);
  int2*    brec  = (int2*)alloc_f((size_t)e * 2);
  int*     rs    = (int*)alloc_f(n + 1);
  int2*    csr   = (int2*)alloc_f((size_t)e * 2);
  float*   dinv  = alloc_f(n);
  __half*  temb  = (__half*)alloc_f((size_t)vocab * 64);  // vocab*128 halves
  __half2* out1  = (__half2*)alloc_f((size_t)n * 64);     // n*128 halves
  (void)ws_size;

  dim3 b256(256);
  int ge = (e + 255) / 256;
  int gagg = (int)(((size_t)n * 64 + 255) / 256);

  hist_kernel<<<bact, b256, 0, stream>>>(dstp, hist, e, chunk, nb);
  colscan_kernel<<<(nb * 64 + 255) / 256, b256, 0, stream>>>(hist, off, tot, nb, bact);
  ebase_kernel<<<1, 1024, 0, stream>>>(tot, ebase, nb);
  scatter_kernel<<<bact, b256, 0, stream>>>(srcp, dstp, weight, labels, off, ebase,
                                            brec, e, chunk);
  bsort_kernel<<<nb, b256, 0, stream>>>(brec, ebase, csr, rs, n);
  deg_kernel<<<gagg, b256, 0, stream>>>(rs, csr, dinv, n);
  scale_kernel<<<ge, b256, 0, stream>>>(csr, dinv, e);
  temb_kernel<<<vocab, 128, 0, stream>>>(emb, W1, temb);
  // layer 1: out1 = relu(A_hat temb[labels] + b1)  (fp16 in/out)
  agg1_kernel<<<gagg, b256, 0, stream>>>(rs, csr, dinv, labels, (const __half2*)temb,
                                         b1, out1, n);
  // layer 2: d_out = (A_hat out1) @ W2 + b2   (agg first, then in-place GEMM)
  agg2_kernel<<<gagg, b256, 0, stream>>>(rs, csr, dinv, out1, (float*)d_out, n);
  gemm_bias_kernel<<<(n + 31) / 32, b256, 0, stream>>>((float*)d_out, W2, b2, n);
}

// Round 7
// 205.994 us; speedup vs baseline: 2.0755x; 1.0613x over previous
//
#include <hip/hip_runtime.h>
#include <hip/hip_fp16.h>

// ---------------------------------------------------------------------------
// 2-layer GCN on MI355X.
//   GCNConv(x) = A_hat (x W) + b = (A_hat x) W + b  (agg and linear commute),
//   and emb[labels]@W1 = (emb@W1)[labels] -> layer 1 gathers from a 256KB
//   fp16 L2-resident table; layer 2 aggregates first, then in-place GEMM.
// CSR build: ZERO global atomics (fabric atomic ceiling ~22G/s). Two-level
// counting sort:
//   K1: per-chunk LDS histogram over 782 dst-buckets (bucket = dst>>6)
//   K2: per-bucket column scan over chunks (wave/bucket, shfl)
//   K2b: bucket-base scan (ebase)
//   K3: scatter into bucket-grouped records; rank via LDS atomic return
//   K4: per-bucket 64-bin sort -> final CSR + rs[] + dinv (weighted degree
//       folded in via LDS float accumulation -- no separate deg pass)
// dinv[src] prescale is applied per-lane in the agg batch phase (independent
// 4B gathers from the 200KB L2-resident dinv array, NOT in the dependent
// broadcast chain) -- no separate scale pass.
// Agg inner loop: batch-load 64 edge records coalesced, shfl-broadcast ->
// gather addresses come from registers -> deep memory-level parallelism.
// out1 and temb fp16 -> 256B gather rows.
// ---------------------------------------------------------------------------

#define CHUNKS 896  // 14*64; chunk = ceil(e/896) = 1786 for e=1.6M (<=1792)

// K1: per-chunk histogram of dst-buckets (nb = ceil(n/64) <= 1024).
__global__ __launch_bounds__(256) void hist_kernel(const int* __restrict__ dst,
                                                   int* __restrict__ hist,
                                                   int e, int chunk, int nb) {
  __shared__ unsigned lh[1024];
  int b = blockIdx.x, t = threadIdx.x;
  int start = b * chunk, end = min(e, start + chunk);
  for (int i = t; i < nb; i += 256) lh[i] = 0;
  __syncthreads();
  for (int i = start + t; i < end; i += 256) atomicAdd(&lh[dst[i] >> 6], 1u);
  __syncthreads();
  for (int k = t; k < nb; k += 256) hist[(size_t)k * CHUNKS + b] = (int)lh[k];
}

// K2: one wave per bucket k: exclusive scan of hist[k][*] over chunks.
__global__ __launch_bounds__(256) void colscan_kernel(const int* __restrict__ hist,
                                                      int* __restrict__ off,
                                                      int* __restrict__ tot,
                                                      int nb, int bact) {
  int k = (blockIdx.x * 256 + threadIdx.x) >> 6;
  int lane = threadIdx.x & 63;
  if (k >= nb) return;
  int carry = 0;
  for (int r = 0; r < CHUNKS / 64; ++r) {
    int b = r * 64 + lane;
    int h = (b < bact) ? hist[(size_t)k * CHUNKS + b] : 0;
    int x = h;
#pragma unroll
    for (int d = 1; d < 64; d <<= 1) {
      int tt = __shfl_up(x, d, 64);
      if (lane >= d) x += tt;
    }
    if (b < bact) off[(size_t)k * CHUNKS + b] = carry + x - h;
    carry += __shfl(x, 63, 64);
  }
  if (lane == 0) tot[k] = carry;
}

// K2b: single block: exclusive scan of tot[nb] -> ebase[nb+1].
__global__ __launch_bounds__(1024) void ebase_kernel(const int* __restrict__ tot,
                                                     int* __restrict__ ebase, int nb) {
  __shared__ int wsum[16];
  int t = threadIdx.x, lane = t & 63, wv = t >> 6;
  int v = (t < nb) ? tot[t] : 0;
  int x = v;
#pragma unroll
  for (int d = 1; d < 64; d <<= 1) {
    int tt = __shfl_up(x, d, 64);
    if (lane >= d) x += tt;
  }
  if (lane == 63) wsum[wv] = x;
  __syncthreads();
  int o = 0;
#pragma unroll
  for (int w = 0; w < 16; ++w) o += (w < wv) ? wsum[w] : 0;
  int excl = x - v + o;
  if (t < nb) ebase[t] = excl;
  if (t == nb - 1) ebase[nb] = excl + v;
}

// K3: scatter edges into bucket-grouped records. Rank within (chunk,bucket)
// via LDS atomic return; pos = ebase[k] + off[k][b] + lrank. No global atomics.
// rec.x = src | dst_local<<16 | label<<22 (unsigned), rec.y = w bits.
__global__ __launch_bounds__(256) void scatter_kernel(
    const int* __restrict__ src, const int* __restrict__ dst,
    const float* __restrict__ w, const int* __restrict__ labels,
    const int* __restrict__ off, const int* __restrict__ ebase,
    int2* __restrict__ brec, int e, int chunk) {
  __shared__ unsigned bincnt[1024];
  int b = blockIdx.x, t = threadIdx.x;
  int start = b * chunk, end = min(e, start + chunk);
  for (int i = t; i < 1024; i += 256) bincnt[i] = 0;
  __syncthreads();
  int s[7], d[7], lb[7], bs[7];
  float wv[7];
#pragma unroll
  for (int u = 0; u < 7; ++u) {
    int i = start + u * 256 + t;
    bool ok = i < end;
    s[u] = ok ? src[i] : 0;
    d[u] = ok ? dst[i] : 0;
    wv[u] = ok ? w[i] : 0.f;
  }
#pragma unroll
  for (int u = 0; u < 7; ++u) lb[u] = labels[s[u]];
#pragma unroll
  for (int u = 0; u < 7; ++u) {
    int k = d[u] >> 6;
    bs[u] = ebase[k] + off[(size_t)k * CHUNKS + b];
  }
#pragma unroll
  for (int u = 0; u < 7; ++u) {
    int i = start + u * 256 + t;
    if (i < end) {
      int k = d[u] >> 6;
      unsigned lr = atomicAdd(&bincnt[k], 1u);
      unsigned rx = (unsigned)s[u] | ((unsigned)(d[u] & 63) << 16) |
                    ((unsigned)lb[u] << 22);
      brec[bs[u] + (int)lr] = make_int2((int)rx, __float_as_int(wv[u]));
    }
  }
}

// K4: per-bucket 64-bin sort: brec -> csr (src|label<<16, w), plus rs[] and
// dinv (weighted-degree fold: rsum via LDS float atomics on the first pass).
__global__ __launch_bounds__(256) void bsort_kernel(const int2* __restrict__ brec,
                                                    const int* __restrict__ ebase,
                                                    int2* __restrict__ csr,
                                                    int* __restrict__ rs,
                                                    float* __restrict__ dinv, int n) {
  __shared__ unsigned h64[64];
  __shared__ unsigned cur[64];
  __shared__ float rsum[64];
  int k = blockIdx.x, t = threadIdx.x;
  int e0 = ebase[k], e1 = ebase[k + 1];
  if (t < 64) { h64[t] = 0; rsum[t] = 0.f; }
  __syncthreads();
  for (int i = e0 + t; i < e1; i += 256) {
    int2 r = brec[i];
    unsigned dl = ((unsigned)r.x >> 16) & 63u;
    atomicAdd(&h64[dl], 1u);
    atomicAdd(&rsum[dl], __int_as_float(r.y));
  }
  __syncthreads();
  if (t < 64) {
    int hv = (int)h64[t];
    int x = hv;
#pragma unroll
    for (int d = 1; d < 64; d <<= 1) {
      int tt = __shfl_up(x, d, 64);
      if (t >= d) x += tt;
    }
    int ex = x - hv;
    cur[t] = (unsigned)(e0 + ex);
    int v = k * 64 + t;
    if (v <= n) rs[v] = e0 + ex;  // last bucket's lane localN writes rs[n]=e
    if (v < n) dinv[v] = rsqrtf(1.0f + rsum[t]);
  }
  __syncthreads();
  for (int i = e0 + t; i < e1; i += 256) {
    int2 r = brec[i];
    unsigned rx = (unsigned)r.x;
    int dl = (int)((rx >> 16) & 63u);
    int pos = (int)atomicAdd(&cur[dl], 1u);
    csr[pos] = make_int2((int)((rx & 0xffffu) | ((rx >> 22) << 16)), r.y);
  }
}

// temb = emb_table @ W1, stored fp16  (vocab x 128) -- 256KB L2-resident table
__global__ void temb_kernel(const float* __restrict__ emb, const float* __restrict__ W1,
                            __half* __restrict__ temb) {
  int r = blockIdx.x, j = threadIdx.x;
  __shared__ float xs[128];
  xs[j] = emb[r * 128 + j];
  __syncthreads();
  float acc = 0.f;
#pragma unroll 8
  for (int k = 0; k < 128; ++k) acc = fmaf(xs[k], W1[k * 128 + j], acc);
  temb[r * 128 + j] = __float2half_rn(acc);
}

// Layer 1: out1 = relu(A_hat temb[labels] + b1), fp16 in/out.
// One wave per node; lane owns features [2*lane, 2*lane+1]. Per-lane
// dinv[src] prescale in the batch phase (independent 4B L2-hit gathers).
__global__ __launch_bounds__(256) void agg1_kernel(
    const int* __restrict__ rs, const int2* __restrict__ csr,
    const float* __restrict__ dinv, const int* __restrict__ labels,
    const __half2* __restrict__ temb, const float* __restrict__ b1,
    __half2* __restrict__ out1, int n) {
  int wid = (blockIdx.x * blockDim.x + threadIdx.x) >> 6;
  int lane = threadIdx.x & 63;
  if (wid >= n) return;
  float di = dinv[wid];
  int selfrow = labels[wid];
  float2 hv = __half22float2(temb[(size_t)selfrow * 64 + lane]);
  float acc0 = hv.x * di, acc1 = hv.y * di;  // self term (x di again at end)
  int r1v = rs[wid + 1];
  for (int base = rs[wid]; base < r1v; base += 64) {
    int s = 0;
    float v = 0.f;
    if (base + lane < r1v) {
      int2 c = csr[base + lane];
      s = c.x;
      v = __int_as_float(c.y) * dinv[c.x & 0xffff];
    }
    int nb = min(64, r1v - base);
    int j = 0;
    for (; j + 8 <= nb; j += 8) {
#pragma unroll
      for (int u = 0; u < 8; ++u) {
        int sj = __shfl(s, j + u, 64);
        float vj = __shfl(v, j + u, 64);
        float2 hs = __half22float2(temb[(size_t)(sj >> 16) * 64 + lane]);
        acc0 = fmaf(hs.x, vj, acc0);
        acc1 = fmaf(hs.y, vj, acc1);
      }
    }
    for (; j < nb; ++j) {
      int sj = __shfl(s, j, 64);
      float vj = __shfl(v, j, 64);
      float2 hs = __half22float2(temb[(size_t)(sj >> 16) * 64 + lane]);
      acc0 = fmaf(hs.x, vj, acc0);
      acc1 = fmaf(hs.y, vj, acc1);
    }
  }
  acc0 = fmaf(acc0, di, b1[2 * lane]);
  acc1 = fmaf(acc1, di, b1[2 * lane + 1]);
  out1[(size_t)wid * 64 + lane] =
      __float22half2_rn(make_float2(fmaxf(acc0, 0.f), fmaxf(acc1, 0.f)));
}

// Layer 2 aggregation: out = A_hat h (fp16 gather source, f32 output).
// Unroll-16 broadcast loop: more outstanding L3 gathers per wave.
__global__ __launch_bounds__(256) void agg2_kernel(
    const int* __restrict__ rs, const int2* __restrict__ csr,
    const float* __restrict__ dinv, const __half2* __restrict__ h,
    float* __restrict__ out, int n) {
  int wid = (blockIdx.x * blockDim.x + threadIdx.x) >> 6;
  int lane = threadIdx.x & 63;
  if (wid >= n) return;
  float di = dinv[wid];
  float2 hv = __half22float2(h[(size_t)wid * 64 + lane]);
  float acc0 = hv.x * di, acc1 = hv.y * di;
  int r1v = rs[wid + 1];
  for (int base = rs[wid]; base < r1v; base += 64) {
    int s = 0;
    float v = 0.f;
    if (base + lane < r1v) {
      int2 c = csr[base + lane];
      s = c.x;
      v = __int_as_float(c.y) * dinv[c.x & 0xffff];
    }
    int nb = min(64, r1v - base);
    int j = 0;
    for (; j + 16 <= nb; j += 16) {
#pragma unroll
      for (int u = 0; u < 16; ++u) {
        int sj = __shfl(s, j + u, 64);
        float vj = __shfl(v, j + u, 64);
        float2 hs = __half22float2(h[(size_t)(sj & 0xffff) * 64 + lane]);
        acc0 = fmaf(hs.x, vj, acc0);
        acc1 = fmaf(hs.y, vj, acc1);
      }
    }
    for (; j + 8 <= nb; j += 8) {
#pragma unroll
      for (int u = 0; u < 8; ++u) {
        int sj = __shfl(s, j + u, 64);
        float vj = __shfl(v, j + u, 64);
        float2 hs = __half22float2(h[(size_t)(sj & 0xffff) * 64 + lane]);
        acc0 = fmaf(hs.x, vj, acc0);
        acc1 = fmaf(hs.y, vj, acc1);
      }
    }
    for (; j < nb; ++j) {
      int sj = __shfl(s, j, 64);
      float vj = __shfl(v, j, 64);
      float2 hs = __half22float2(h[(size_t)(sj & 0xffff) * 64 + lane]);
      acc0 = fmaf(hs.x, vj, acc0);
      acc1 = fmaf(hs.y, vj, acc1);
    }
  }
  *(float2*)(out + (size_t)wid * 128 + 2 * lane) = make_float2(acc0 * di, acc1 * di);
}

// In-place: y[rb..rb+31] = y[rb..rb+31] @ W + b. Each block only touches its
// own 32 rows (staged to LDS before overwrite) -> in-place safe.
__global__ __launch_bounds__(256) void gemm_bias_kernel(float* __restrict__ y,
                                                        const float* __restrict__ W,
                                                        const float* __restrict__ bias,
                                                        int n) {
  __shared__ float xs[32][128];
  int tid = threadIdx.x;
  int tc = tid & 31;
  int tr = tid >> 5;
  int rb = blockIdx.x * 32;
  {
    const float4* xg = (const float4*)(y + (size_t)rb * 128);
    float4* xls = (float4*)&xs[0][0];
#pragma unroll
    for (int i = 0; i < 4; ++i) {
      int idx = tid + i * 256;  // float4 index; row = idx>>5
      int row = rb + (idx >> 5);
      float4 val = (row < n) ? xg[idx] : make_float4(0.f, 0.f, 0.f, 0.f);
      xls[idx] = val;
    }
  }
  __syncthreads();
  int j0 = tc * 4;
  float4 b4 = *(const float4*)(bias + j0);
  float acc[4][4];
#pragma unroll
  for (int r = 0; r < 4; ++r) {
    acc[r][0] = b4.x; acc[r][1] = b4.y; acc[r][2] = b4.z; acc[r][3] = b4.w;
  }
#pragma unroll 4
  for (int k = 0; k < 128; ++k) {
    float4 w4 = *(const float4*)(W + k * 128 + j0);
#pragma unroll
    for (int r = 0; r < 4; ++r) {
      float xv = xs[tr * 4 + r][k];
      acc[r][0] = fmaf(xv, w4.x, acc[r][0]);
      acc[r][1] = fmaf(xv, w4.y, acc[r][1]);
      acc[r][2] = fmaf(xv, w4.z, acc[r][2]);
      acc[r][3] = fmaf(xv, w4.w, acc[r][3]);
    }
  }
#pragma unroll
  for (int r = 0; r < 4; ++r) {
    int row = rb + tr * 4 + r;
    if (row < n)
      *(float4*)(y + (size_t)row * 128 + j0) =
          make_float4(acc[r][0], acc[r][1], acc[r][2], acc[r][3]);
  }
}

extern "C" void kernel_launch(void* const* d_in, const int* in_sizes, int n_in,
                              void* d_out, int out_size, void* d_ws, size_t ws_size,
                              hipStream_t stream) {
  const int* labels = (const int*)d_in[0];
  const int* edge_index = (const int*)d_in[1];
  const float* weight = (const float*)d_in[2];
  const float* emb = (const float*)d_in[3];
  const float* W1 = (const float*)d_in[4];
  const float* b1 = (const float*)d_in[5];
  const float* W2 = (const float*)d_in[6];
  const float* b2 = (const float*)d_in[7];

  int n = in_sizes[0];
  int e = in_sizes[1] / 2;
  int vocab = in_sizes[3] / 128;
  const int* srcp = edge_index;
  const int* dstp = edge_index + e;

  int nb = (n + 63) >> 6;                 // dst buckets (782)
  int chunk = (e + CHUNKS - 1) / CHUNKS;  // 1786 (<=1792 for unroll-7 staging)
  int bact = (e + chunk - 1) / chunk;     // actual chunks (<= CHUNKS)

  // workspace carve-up (float elements, 256-aligned). Total ~45 MiB.
  float* ws = (float*)d_ws;
  size_t o = 0;
  auto alloc_f = [&](size_t c) { float* p = ws + o; o += (c + 255) & ~(size_t)255; return p; };
  int*     hist  = (int*)alloc_f((size_t)nb * CHUNKS);
  int*     off   = (int*)alloc_f((size_t)nb * CHUNKS);
  int*     tot   = (int*)alloc_f(nb);
  int*     ebase = (int*)alloc_f(nb + 1);
  int2*    brec  = (int2*)alloc_f((size_t)e * 2);
  int*     rs    = (int*)alloc_f(n + 1);
  int2*    csr   = (int2*)alloc_f((size_t)e * 2);
  float*   dinv  = alloc_f(n);
  __half*  temb  = (__half*)alloc_f((size_t)vocab * 64);  // vocab*128 halves
  __half2* out1  = (__half2*)alloc_f((size_t)n * 64);     // n*128 halves
  (void)ws_size;

  dim3 b256(256);
  int gagg = (int)(((size_t)n * 64 + 255) / 256);

  hist_kernel<<<bact, b256, 0, stream>>>(dstp, hist, e, chunk, nb);
  colscan_kernel<<<(nb * 64 + 255) / 256, b256, 0, stream>>>(hist, off, tot, nb, bact);
  ebase_kernel<<<1, 1024, 0, stream>>>(tot, ebase, nb);
  scatter_kernel<<<bact, b256, 0, stream>>>(srcp, dstp, weight, labels, off, ebase,
                                            brec, e, chunk);
  bsort_kernel<<<nb, b256, 0, stream>>>(brec, ebase, csr, rs, dinv, n);
  temb_kernel<<<vocab, 128, 0, stream>>>(emb, W1, temb);
  // layer 1: out1 = relu(A_hat temb[labels] + b1)  (fp16 in/out)
  agg1_kernel<<<gagg, b256, 0, stream>>>(rs, csr, dinv, labels, (const __half2*)temb,
                                         b1, out1, n);
  // layer 2: d_out = (A_hat out1) @ W2 + b2   (agg first, then in-place GEMM)
  agg2_kernel<<<gagg, b256, 0, stream>>>(rs, csr, dinv, out1, (float*)d_out, n);
  gemm_bias_kernel<<<(n + 31) / 32, b256, 0, stream>>>((float*)d_out, W2, b2, n);
}

// Round 8
// 200.483 us; speedup vs baseline: 2.1326x; 1.0275x over previous
//
#include <hip/hip_runtime.h>
#include <hip/hip_fp16.h>

// ---------------------------------------------------------------------------
// 2-layer GCN on MI355X.
//   GCNConv(x) = A_hat (x W) + b = (A_hat x) W + b  (agg and linear commute),
//   and emb[labels]@W1 = (emb@W1)[labels] -> layer 1 gathers from a 256KB
//   fp16 L2-resident table; layer 2 aggregates first, then in-place GEMM.
// CSR build: ZERO global atomics (fabric atomic ceiling ~22G/s). Two-level
// counting sort (K1 hist / K2 colscan / K2b ebase / K3 scatter / K4 bsort
// with weighted-degree fold -> dinv). CHUNKS=256 so scatter write runs are
// ~8 edges (64B) -- lower write amplification than fine chunks.
// Agg kernels: PAIR-GATHER -- wave splits into 2x32 lanes; each lane owns
// 4 features (8B half4 gather), halves process edges j/j+1 via bpermute with
// per-lane index. Halves the gather instr count at same VGPR -> 2x edges in
// flight (the aggs are latency x MLP bound: ~600ns L3, ~41k reqs in flight).
// dinv[src] prescale per-lane in the batch phase; out1/temb fp16 (256B rows).
// ---------------------------------------------------------------------------

#define CHUNKS 256  // chunk = ceil(e/256) = 6250 for e=1.6M

// K1: per-chunk histogram of dst-buckets (nb = ceil(n/64) <= 1024).
__global__ __launch_bounds__(256) void hist_kernel(const int* __restrict__ dst,
                                                   int* __restrict__ hist,
                                                   int e, int chunk, int nb) {
  __shared__ unsigned lh[1024];
  int b = blockIdx.x, t = threadIdx.x;
  int start = b * chunk, end = min(e, start + chunk);
  for (int i = t; i < nb; i += 256) lh[i] = 0;
  __syncthreads();
  for (int i = start + t; i < end; i += 256) atomicAdd(&lh[dst[i] >> 6], 1u);
  __syncthreads();
  for (int k = t; k < nb; k += 256) hist[(size_t)k * CHUNKS + b] = (int)lh[k];
}

// K2: one wave per bucket k: exclusive scan of hist[k][*] over chunks.
__global__ __launch_bounds__(256) void colscan_kernel(const int* __restrict__ hist,
                                                      int* __restrict__ off,
                                                      int* __restrict__ tot,
                                                      int nb, int bact) {
  int k = (blockIdx.x * 256 + threadIdx.x) >> 6;
  int lane = threadIdx.x & 63;
  if (k >= nb) return;
  int carry = 0;
  for (int r = 0; r < CHUNKS / 64; ++r) {
    int b = r * 64 + lane;
    int h = (b < bact) ? hist[(size_t)k * CHUNKS + b] : 0;
    int x = h;
#pragma unroll
    for (int d = 1; d < 64; d <<= 1) {
      int tt = __shfl_up(x, d, 64);
      if (lane >= d) x += tt;
    }
    if (b < bact) off[(size_t)k * CHUNKS + b] = carry + x - h;
    carry += __shfl(x, 63, 64);
  }
  if (lane == 0) tot[k] = carry;
}

// K2b: single block: exclusive scan of tot[nb] -> ebase[nb+1].
__global__ __launch_bounds__(1024) void ebase_kernel(const int* __restrict__ tot,
                                                     int* __restrict__ ebase, int nb) {
  __shared__ int wsum[16];
  int t = threadIdx.x, lane = t & 63, wv = t >> 6;
  int v = (t < nb) ? tot[t] : 0;
  int x = v;
#pragma unroll
  for (int d = 1; d < 64; d <<= 1) {
    int tt = __shfl_up(x, d, 64);
    if (lane >= d) x += tt;
  }
  if (lane == 63) wsum[wv] = x;
  __syncthreads();
  int o = 0;
#pragma unroll
  for (int w = 0; w < 16; ++w) o += (w < wv) ? wsum[w] : 0;
  int excl = x - v + o;
  if (t < nb) ebase[t] = excl;
  if (t == nb - 1) ebase[nb] = excl + v;
}

// K3: scatter edges into bucket-grouped records. Rank within (chunk,bucket)
// via LDS atomic return (cumulative across batches); pos = ebase[k]+off[k][b]
// + lrank. No global atomics. rec.x = src | dst_local<<16 | label<<22.
__global__ __launch_bounds__(256) void scatter_kernel(
    const int* __restrict__ src, const int* __restrict__ dst,
    const float* __restrict__ w, const int* __restrict__ labels,
    const int* __restrict__ off, const int* __restrict__ ebase,
    int2* __restrict__ brec, int e, int chunk) {
  __shared__ unsigned bincnt[1024];
  int b = blockIdx.x, t = threadIdx.x;
  int start = b * chunk, end = min(e, start + chunk);
  for (int i = t; i < 1024; i += 256) bincnt[i] = 0;
  __syncthreads();
  for (int bs0 = start; bs0 < end; bs0 += 1792) {
    int bend = min(end, bs0 + 1792);
    int s[7], d[7], lb[7], ps[7];
    float wv[7];
#pragma unroll
    for (int u = 0; u < 7; ++u) {
      int i = bs0 + u * 256 + t;
      bool ok = i < bend;
      s[u] = ok ? src[i] : 0;
      d[u] = ok ? dst[i] : 0;
      wv[u] = ok ? w[i] : 0.f;
    }
#pragma unroll
    for (int u = 0; u < 7; ++u) lb[u] = labels[s[u]];
#pragma unroll
    for (int u = 0; u < 7; ++u) {
      int k = d[u] >> 6;
      ps[u] = ebase[k] + off[(size_t)k * CHUNKS + b];
    }
#pragma unroll
    for (int u = 0; u < 7; ++u) {
      int i = bs0 + u * 256 + t;
      if (i < bend) {
        int k = d[u] >> 6;
        unsigned lr = atomicAdd(&bincnt[k], 1u);
        unsigned rx = (unsigned)s[u] | ((unsigned)(d[u] & 63) << 16) |
                      ((unsigned)lb[u] << 22);
        brec[ps[u] + (int)lr] = make_int2((int)rx, __float_as_int(wv[u]));
      }
    }
  }
}

// K4: per-bucket 64-bin sort: brec -> csr (src|label<<16, w), plus rs[] and
// dinv (weighted-degree fold: rsum via LDS float atomics on the first pass).
__global__ __launch_bounds__(256) void bsort_kernel(const int2* __restrict__ brec,
                                                    const int* __restrict__ ebase,
                                                    int2* __restrict__ csr,
                                                    int* __restrict__ rs,
                                                    float* __restrict__ dinv, int n) {
  __shared__ unsigned h64[64];
  __shared__ unsigned cur[64];
  __shared__ float rsum[64];
  int k = blockIdx.x, t = threadIdx.x;
  int e0 = ebase[k], e1 = ebase[k + 1];
  if (t < 64) { h64[t] = 0; rsum[t] = 0.f; }
  __syncthreads();
  for (int i = e0 + t; i < e1; i += 256) {
    int2 r = brec[i];
    unsigned dl = ((unsigned)r.x >> 16) & 63u;
    atomicAdd(&h64[dl], 1u);
    atomicAdd(&rsum[dl], __int_as_float(r.y));
  }
  __syncthreads();
  if (t < 64) {
    int hv = (int)h64[t];
    int x = hv;
#pragma unroll
    for (int d = 1; d < 64; d <<= 1) {
      int tt = __shfl_up(x, d, 64);
      if (t >= d) x += tt;
    }
    int ex = x - hv;
    cur[t] = (unsigned)(e0 + ex);
    int v = k * 64 + t;
    if (v <= n) rs[v] = e0 + ex;  // last bucket's lane localN writes rs[n]=e
    if (v < n) dinv[v] = rsqrtf(1.0f + rsum[t]);
  }
  __syncthreads();
  for (int i = e0 + t; i < e1; i += 256) {
    int2 r = brec[i];
    unsigned rx = (unsigned)r.x;
    int dl = (int)((rx >> 16) & 63u);
    int pos = (int)atomicAdd(&cur[dl], 1u);
    csr[pos] = make_int2((int)((rx & 0xffffu) | ((rx >> 22) << 16)), r.y);
  }
}

// temb = emb_table @ W1, stored fp16  (vocab x 128) -- 256KB L2-resident table
__global__ void temb_kernel(const float* __restrict__ emb, const float* __restrict__ W1,
                            __half* __restrict__ temb) {
  int r = blockIdx.x, j = threadIdx.x;
  __shared__ float xs[128];
  xs[j] = emb[r * 128 + j];
  __syncthreads();
  float acc = 0.f;
#pragma unroll 8
  for (int k = 0; k < 128; ++k) acc = fmaf(xs[k], W1[k * 128 + j], acc);
  temb[r * 128 + j] = __float2half_rn(acc);
}

// unpack 4 halves (loaded as float2, 8B) -> two float2
__device__ __forceinline__ void unpack4(float2 raw, float2& a, float2& b) {
  union { float f; __half2 h; } u0, u1;
  u0.f = raw.x;
  u1.f = raw.y;
  a = __half22float2(u0.h);
  b = __half22float2(u1.h);
}

// Layer 1: out1 = relu(A_hat temb[labels] + b1), fp16 in/out. Pair-gather:
// half = lane>>5 handles edges j+half; lane owns features 4*fl..4*fl+3.
__global__ __launch_bounds__(256) void agg1_kernel(
    const int* __restrict__ rs, const int2* __restrict__ csr,
    const float* __restrict__ dinv, const int* __restrict__ labels,
    const __half* __restrict__ temb, const float* __restrict__ b1,
    __half* __restrict__ out1, int n) {
  int wid = (blockIdx.x * blockDim.x + threadIdx.x) >> 6;
  int lane = threadIdx.x & 63;
  if (wid >= n) return;
  int half = lane >> 5, fl = lane & 31;
  float di = dinv[wid];
  float acc0, acc1, acc2, acc3;
  {
    int selfrow = labels[wid];
    float2 raw = ((const float2*)(temb + (size_t)selfrow * 128))[fl];
    float2 a, b;
    unpack4(raw, a, b);
    float ss = half ? 0.f : di;  // self term once (half 0 only)
    acc0 = a.x * ss; acc1 = a.y * ss; acc2 = b.x * ss; acc3 = b.y * ss;
  }
  int r1v = rs[wid + 1];
  for (int base = rs[wid]; base < r1v; base += 64) {
    int s = 0;
    float v = 0.f;
    if (base + lane < r1v) {
      int2 c = csr[base + lane];
      s = c.x;
      v = __int_as_float(c.y) * dinv[c.x & 0xffff];
    }
    int nb = min(64, r1v - base);
    int j = 0;
    for (; j + 16 <= nb; j += 16) {
#pragma unroll
      for (int u = 0; u < 8; ++u) {
        int jj = j + 2 * u + half;
        int sj = __shfl(s, jj, 64);
        float vj = __shfl(v, jj, 64);
        float2 raw = ((const float2*)(temb + (size_t)(sj >> 16) * 128))[fl];
        float2 a, b;
        unpack4(raw, a, b);
        acc0 = fmaf(a.x, vj, acc0); acc1 = fmaf(a.y, vj, acc1);
        acc2 = fmaf(b.x, vj, acc2); acc3 = fmaf(b.y, vj, acc3);
      }
    }
    for (; j + 2 <= nb; j += 2) {
      int jj = j + half;
      int sj = __shfl(s, jj, 64);
      float vj = __shfl(v, jj, 64);
      float2 raw = ((const float2*)(temb + (size_t)(sj >> 16) * 128))[fl];
      float2 a, b;
      unpack4(raw, a, b);
      acc0 = fmaf(a.x, vj, acc0); acc1 = fmaf(a.y, vj, acc1);
      acc2 = fmaf(b.x, vj, acc2); acc3 = fmaf(b.y, vj, acc3);
    }
    if (j < nb) {  // leftover single edge: half 1 contributes 0
      int sj = __shfl(s, j, 64);
      float vj0 = __shfl(v, j, 64);
      float vj = half ? 0.f : vj0;
      float2 raw = ((const float2*)(temb + (size_t)(sj >> 16) * 128))[fl];
      float2 a, b;
      unpack4(raw, a, b);
      acc0 = fmaf(a.x, vj, acc0); acc1 = fmaf(a.y, vj, acc1);
      acc2 = fmaf(b.x, vj, acc2); acc3 = fmaf(b.y, vj, acc3);
    }
  }
  acc0 += __shfl_xor(acc0, 32, 64);
  acc1 += __shfl_xor(acc1, 32, 64);
  acc2 += __shfl_xor(acc2, 32, 64);
  acc3 += __shfl_xor(acc3, 32, 64);
  if (half == 0) {
    float4 b4 = ((const float4*)b1)[fl];
    acc0 = fmaxf(fmaf(acc0, di, b4.x), 0.f);
    acc1 = fmaxf(fmaf(acc1, di, b4.y), 0.f);
    acc2 = fmaxf(fmaf(acc2, di, b4.z), 0.f);
    acc3 = fmaxf(fmaf(acc3, di, b4.w), 0.f);
    union { float2 f2; __half2 h2[2]; } o;
    o.h2[0] = __float22half2_rn(make_float2(acc0, acc1));
    o.h2[1] = __float22half2_rn(make_float2(acc2, acc3));
    ((float2*)(out1 + (size_t)wid * 128))[fl] = o.f2;
  }
}

// Layer 2 aggregation: out = A_hat h (fp16 gather source, f32 output).
// Same pair-gather structure.
__global__ __launch_bounds__(256) void agg2_kernel(
    const int* __restrict__ rs, const int2* __restrict__ csr,
    const float* __restrict__ dinv, const __half* __restrict__ h,
    float* __restrict__ out, int n) {
  int wid = (blockIdx.x * blockDim.x + threadIdx.x) >> 6;
  int lane = threadIdx.x & 63;
  if (wid >= n) return;
  int half = lane >> 5, fl = lane & 31;
  float di = dinv[wid];
  float acc0, acc1, acc2, acc3;
  {
    float2 raw = ((const float2*)(h + (size_t)wid * 128))[fl];
    float2 a, b;
    unpack4(raw, a, b);
    float ss = half ? 0.f : di;
    acc0 = a.x * ss; acc1 = a.y * ss; acc2 = b.x * ss; acc3 = b.y * ss;
  }
  int r1v = rs[wid + 1];
  for (int base = rs[wid]; base < r1v; base += 64) {
    int s = 0;
    float v = 0.f;
    if (base + lane < r1v) {
      int2 c = csr[base + lane];
      s = c.x;
      v = __int_as_float(c.y) * dinv[c.x & 0xffff];
    }
    int nb = min(64, r1v - base);
    int j = 0;
    for (; j + 16 <= nb; j += 16) {
#pragma unroll
      for (int u = 0; u < 8; ++u) {
        int jj = j + 2 * u + half;
        int sj = __shfl(s, jj, 64);
        float vj = __shfl(v, jj, 64);
        float2 raw = ((const float2*)(h + (size_t)(sj & 0xffff) * 128))[fl];
        float2 a, b;
        unpack4(raw, a, b);
        acc0 = fmaf(a.x, vj, acc0); acc1 = fmaf(a.y, vj, acc1);
        acc2 = fmaf(b.x, vj, acc2); acc3 = fmaf(b.y, vj, acc3);
      }
    }
    for (; j + 2 <= nb; j += 2) {
      int jj = j + half;
      int sj = __shfl(s, jj, 64);
      float vj = __shfl(v, jj, 64);
      float2 raw = ((const float2*)(h + (size_t)(sj & 0xffff) * 128))[fl];
      float2 a, b;
      unpack4(raw, a, b);
      acc0 = fmaf(a.x, vj, acc0); acc1 = fmaf(a.y, vj, acc1);
      acc2 = fmaf(b.x, vj, acc2); acc3 = fmaf(b.y, vj, acc3);
    }
    if (j < nb) {
      int sj = __shfl(s, j, 64);
      float vj0 = __shfl(v, j, 64);
      float vj = half ? 0.f : vj0;
      float2 raw = ((const float2*)(h + (size_t)(sj & 0xffff) * 128))[fl];
      float2 a, b;
      unpack4(raw, a, b);
      acc0 = fmaf(a.x, vj, acc0); acc1 = fmaf(a.y, vj, acc1);
      acc2 = fmaf(b.x, vj, acc2); acc3 = fmaf(b.y, vj, acc3);
    }
  }
  acc0 += __shfl_xor(acc0, 32, 64);
  acc1 += __shfl_xor(acc1, 32, 64);
  acc2 += __shfl_xor(acc2, 32, 64);
  acc3 += __shfl_xor(acc3, 32, 64);
  if (half == 0) {
    ((float4*)(out + (size_t)wid * 128))[fl] =
        make_float4(acc0 * di, acc1 * di, acc2 * di, acc3 * di);
  }
}

// In-place: y[rb..rb+31] = y[rb..rb+31] @ W + b. Each block only touches its
// own 32 rows (staged to LDS before overwrite) -> in-place safe.
__global__ __launch_bounds__(256) void gemm_bias_kernel(float* __restrict__ y,
                                                        const float* __restrict__ W,
                                                        const float* __restrict__ bias,
                                                        int n) {
  __shared__ float xs[32][128];
  int tid = threadIdx.x;
  int tc = tid & 31;
  int tr = tid >> 5;
  int rb = blockIdx.x * 32;
  {
    const float4* xg = (const float4*)(y + (size_t)rb * 128);
    float4* xls = (float4*)&xs[0][0];
#pragma unroll
    for (int i = 0; i < 4; ++i) {
      int idx = tid + i * 256;  // float4 index; row = idx>>5
      int row = rb + (idx >> 5);
      float4 val = (row < n) ? xg[idx] : make_float4(0.f, 0.f, 0.f, 0.f);
      xls[idx] = val;
    }
  }
  __syncthreads();
  int j0 = tc * 4;
  float4 b4 = *(const float4*)(bias + j0);
  float acc[4][4];
#pragma unroll
  for (int r = 0; r < 4; ++r) {
    acc[r][0] = b4.x; acc[r][1] = b4.y; acc[r][2] = b4.z; acc[r][3] = b4.w;
  }
#pragma unroll 4
  for (int k = 0; k < 128; ++k) {
    float4 w4 = *(const float4*)(W + k * 128 + j0);
#pragma unroll
    for (int r = 0; r < 4; ++r) {
      float xv = xs[tr * 4 + r][k];
      acc[r][0] = fmaf(xv, w4.x, acc[r][0]);
      acc[r][1] = fmaf(xv, w4.y, acc[r][1]);
      acc[r][2] = fmaf(xv, w4.z, acc[r][2]);
      acc[r][3] = fmaf(xv, w4.w, acc[r][3]);
    }
  }
#pragma unroll
  for (int r = 0; r < 4; ++r) {
    int row = rb + tr * 4 + r;
    if (row < n)
      *(float4*)(y + (size_t)row * 128 + j0) =
          make_float4(acc[r][0], acc[r][1], acc[r][2], acc[r][3]);
  }
}

extern "C" void kernel_launch(void* const* d_in, const int* in_sizes, int n_in,
                              void* d_out, int out_size, void* d_ws, size_t ws_size,
                              hipStream_t stream) {
  const int* labels = (const int*)d_in[0];
  const int* edge_index = (const int*)d_in[1];
  const float* weight = (const float*)d_in[2];
  const float* emb = (const float*)d_in[3];
  const float* W1 = (const float*)d_in[4];
  const float* b1 = (const float*)d_in[5];
  const float* W2 = (const float*)d_in[6];
  const float* b2 = (const float*)d_in[7];

  int n = in_sizes[0];
  int e = in_sizes[1] / 2;
  int vocab = in_sizes[3] / 128;
  const int* srcp = edge_index;
  const int* dstp = edge_index + e;

  int nb = (n + 63) >> 6;                 // dst buckets (782)
  int chunk = (e + CHUNKS - 1) / CHUNKS;  // 6250
  int bact = (e + chunk - 1) / chunk;     // actual chunks (<= CHUNKS)

  // workspace carve-up (float elements, 256-aligned). Total ~42 MiB.
  float* ws = (float*)d_ws;
  size_t o = 0;
  auto alloc_f = [&](size_t c) { float* p = ws + o; o += (c + 255) & ~(size_t)255; return p; };
  int*    hist  = (int*)alloc_f((size_t)nb * CHUNKS);
  int*    off   = (int*)alloc_f((size_t)nb * CHUNKS);
  int*    tot   = (int*)alloc_f(nb);
  int*    ebase = (int*)alloc_f(nb + 1);
  int2*   brec  = (int2*)alloc_f((size_t)e * 2);
  int*    rs    = (int*)alloc_f(n + 1);
  int2*   csr   = (int2*)alloc_f((size_t)e * 2);
  float*  dinv  = alloc_f(n);
  __half* temb  = (__half*)alloc_f((size_t)vocab * 64);  // vocab*128 halves
  __half* out1  = (__half*)alloc_f((size_t)n * 64);      // n*128 halves
  (void)ws_size;

  dim3 b256(256);
  int gagg = (int)(((size_t)n * 64 + 255) / 256);

  hist_kernel<<<bact, b256, 0, stream>>>(dstp, hist, e, chunk, nb);
  colscan_kernel<<<(nb * 64 + 255) / 256, b256, 0, stream>>>(hist, off, tot, nb, bact);
  ebase_kernel<<<1, 1024, 0, stream>>>(tot, ebase, nb);
  scatter_kernel<<<bact, b256, 0, stream>>>(srcp, dstp, weight, labels, off, ebase,
                                            brec, e, chunk);
  bsort_kernel<<<nb, b256, 0, stream>>>(brec, ebase, csr, rs, dinv, n);
  temb_kernel<<<vocab, 128, 0, stream>>>(emb, W1, temb);
  // layer 1: out1 = relu(A_hat temb[labels] + b1)  (fp16 in/out)
  agg1_kernel<<<gagg, b256, 0, stream>>>(rs, csr, dinv, labels, temb, b1, out1, n);
  // layer 2: d_out = (A_hat out1) @ W2 + b2   (agg first, then in-place GEMM)
  agg2_kernel<<<gagg, b256, 0, stream>>>(rs, csr, dinv, out1, (float*)d_out, n);
  gemm_bias_kernel<<<(n + 31) / 32, b256, 0, stream>>>((float*)d_out, W2, b2, n);
}